// Round 3
// baseline (342.020 us; speedup 1.0000x reference)
//
#include <hip/hip_runtime.h>
#include <hip/hip_runtime_api.h>
#include <math.h>

#define NBATCH 2
#define QQ     131072
#define HH     64
#define WWID   2048
#define CC     64
#define HWSZ   (HH*WWID)   /* 131072 = 2^17 */

constexpr int ROWS    = 128;   // rows per block
constexpr int THREADS = 1024;  // 16 waves, 4M x 4N wave grid

// A: 128 rows x 512 B (256 bf16), XOR-swizzled; byte ^= (row&7)<<4
constexpr int ASTR_B = 512;

// dynamic-LDS byte offsets
constexpr int WBUF    = 32768;             // one W chunk buffer (max: N=256,K=64)
constexpr int OFF_A   = 0;                 // 65536 B
constexpr int OFF_W   = 65536;             // 2 x 32768 B
constexpr int OFF_TAP = OFF_W + 2*WBUF;    // tap[128][4] int  = 2048 B
constexpr int OFF_PXY = OFF_TAP + 2048;    // pxy[128][4] f32  = 2048 B
constexpr int OFF_E3  = OFF_PXY + 2048;    // ew3 64x4 f32     = 1024 B
constexpr int LDS_BYTES = OFF_E3 + 1024;   // 136192 B -> 1 block/CU, 16 waves

// packed fragment-layout weight offsets in elements (Kp = K padded to 64)
constexpr int WOFF_PE0 = 0;       // N=64,  Kp=64   -> 4096
constexpr int WOFF_PE1 = 4096;    // N=128, Kp=64   -> 8192
constexpr int WOFF_PE2 = 12288;   // N=256, Kp=128  -> 32768
constexpr int WOFF_E0  = 45056;   // N=256, Kp=256  -> 65536
constexpr int WOFF_E1  = 110592;  // N=128, Kp=256  -> 32768
constexpr int WOFF_E2  = 143360;  // N=64,  Kp=128  -> 8192
constexpr int WTOTAL   = 151552;

typedef __attribute__((ext_vector_type(8))) short bf16x8;
typedef __attribute__((ext_vector_type(4))) float f32x4;

__device__ __forceinline__ ushort f2bf(float f) {
    union { float f; unsigned u; } x; x.f = f;
    unsigned r = x.u + 0x7fffu + ((x.u >> 16) & 1u);   // RNE
    return (ushort)(r >> 16);
}
__device__ __forceinline__ float bf2f(ushort h) {
    union { unsigned u; float f; } x; x.u = ((unsigned)h) << 16;
    return x.f;
}

// swizzled A byte address (colByte may be 2-byte granular; XOR flips bits 4-6)
__device__ __forceinline__ int swA(int row, int colByte) {
    return row * ASTR_B + (colByte ^ ((row & 7) << 4));
}

// async global->LDS, 16 B per lane (dst = wave-uniform base + lane*16)
__device__ __forceinline__ void gload_lds16(const void* g, void* l) {
    __builtin_amdgcn_global_load_lds(
        (const __attribute__((address_space(1))) unsigned int*)g,
        (__attribute__((address_space(3))) unsigned int*)l, 16, 0, 0);
}

// ---------------------------------------------------------------------------
// Weight prep: fp32 [K][N] -> bf16 MFMA-fragment-packed [chunks][tiles][512]
// tile = 16 cols x 32 k, lane-ordered: elem(lane,j) = W[k0+(lane>>4)*8+j][n0+(lane&15)]
// chunk = 64 k-wide: tiles ordered (n>>4)*2 + kk
// ---------------------------------------------------------------------------
struct WDesc { const float* src; int K; int N; int kshift; };  // Kp = 1<<kshift
struct WPack { WDesc d[6]; };

__global__ __launch_bounds__(256) void prep_weights(WPack p, ushort* __restrict__ dst)
{
    int e = blockIdx.x * 256 + threadIdx.x;
    int off = 0;
    #pragma unroll
    for (int L = 0; L < 6; ++L) {
        const int Kp = 1 << p.d[L].kshift;
        const int N  = p.d[L].N;
        const int sz = N * Kp;
        if (e < sz) {
            const int n = e / Kp;        // Kp is pow2 but / is fine
            const int k = e & (Kp - 1);
            const float v = (k < p.d[L].K) ? p.d[L].src[(size_t)k * N + n] : 0.f;
            const int chunk = k >> 6;
            const int kk    = (k >> 5) & 1;
            const int tile  = chunk * ((N >> 4) * 2) + (n >> 4) * 2 + kk;
            const int lane  = (n & 15) + (((k >> 3) & 3) << 4);
            const int j     = k & 7;
            dst[off + tile * 512 + lane * 8 + j] = f2bf(v);
            return;
        }
        e -= sz; off += sz;
    }
}

// ---------------------------------------------------------------------------
// Feat prep: NCHW f32 -> NHWC bf16, plus xy = sqrt(d1^2+d2^2)
// ---------------------------------------------------------------------------
__global__ __launch_bounds__(256) void prep_feat(
    const float* __restrict__ depth, const float* __restrict__ feat,
    ushort* __restrict__ nhwc, float* __restrict__ xy)
{
    const int idx = blockIdx.x * 256 + threadIdx.x;
    const int b   = idx >> 17;
    const int yx  = idx & (HWSZ - 1);

    const float d1 = depth[(b * 3 + 1) * HWSZ + yx];
    const float d2 = depth[(b * 3 + 2) * HWSZ + yx];
    xy[idx] = sqrtf(d1 * d1 + d2 * d2);

    const float* fp = feat + (size_t)b * CC * HWSZ + yx;
    ushort* op = nhwc + (size_t)idx * CC;
    #pragma unroll
    for (int c = 0; c < CC; c += 8) {
        union { uint4 v; ushort u[8]; } t;
        #pragma unroll
        for (int j = 0; j < 8; ++j) t.u[j] = f2bf(fp[(size_t)(c + j) * HWSZ]);
        *(uint4*)(op + c) = t.v;
    }
}

// ---------------------------------------------------------------------------
// One dense layer, in place on A (bf16, swizzled LDS). 16 waves = 4M x 4N.
// Wave tile 32 rows x N/4 cols, 16x16x32 MFMA. W double-buffered in LDS via
// global_load_lds with one-chunk-ahead prefetch (incl. next layer's chunk 0).
// ---------------------------------------------------------------------------
template <int K, int N, bool RELU>
__device__ __forceinline__ void dense_layer(
    char* __restrict__ lds, int& buf,
    const ushort* __restrict__ Wt, const float* __restrict__ Bg,
    const ushort* __restrict__ nextWt, int nextBytes, int tid)
{
    constexpr int TN  = N / 64;        // 16-col tiles per wave
    constexpr int NCH = K / 64;        // 64-wide K chunks
    constexpr int CHB = N * 128;       // bytes per chunk

    char* sA = lds + OFF_A;
    const int lane = tid & 63, wv = tid >> 6;
    const int wm = wv >> 2, wn = wv & 3;
    const int row0 = wm * 32;
    const int col0 = wn * (N / 4);
    const int lrow = lane & 15;
    const int lkb  = (lane >> 4) * 16;   // byte offset of this lane's 8 bf16 in k

    f32x4 acc[2][TN];
    #pragma unroll
    for (int tm = 0; tm < 2; ++tm)
        #pragma unroll
        for (int tn = 0; tn < TN; ++tn) acc[tm][tn] = (f32x4){0.f, 0.f, 0.f, 0.f};

    #pragma unroll
    for (int c = 0; c < NCH; ++c) {
        char* cur = lds + OFF_W + buf * WBUF;
        char* nxt = lds + OFF_W + (buf ^ 1) * WBUF;

        // prefetch next chunk (or next layer's chunk 0) into nxt
        const char* src = (c + 1 < NCH) ? (const char*)Wt + (size_t)(c + 1) * CHB
                                        : (const char*)nextWt;
        const int nb = (c + 1 < NCH) ? CHB : nextBytes;
        for (int u = wv; u * 1024 < nb; u += 16)
            gload_lds16(src + (size_t)u * 1024 + lane * 16, nxt + u * 1024);

        // compute on cur (resident: waited before previous barrier)
        #pragma unroll
        for (int ks = 0; ks < 64; ks += 32) {
            const int cb = (c * 64 + ks) * 2 + lkb;
            const bf16x8 a0 = *(const bf16x8*)(sA + swA(row0 +      lrow, cb));
            const bf16x8 a1 = *(const bf16x8*)(sA + swA(row0 + 16 + lrow, cb));
            #pragma unroll
            for (int tn = 0; tn < TN; ++tn) {
                const int tile = (wn * (N >> 6) + tn) * 2 + (ks >> 5);
                const bf16x8 bw = *(const bf16x8*)(cur + tile * 1024 + lane * 16);
                acc[0][tn] = __builtin_amdgcn_mfma_f32_16x16x32_bf16(a0, bw, acc[0][tn], 0, 0, 0);
                acc[1][tn] = __builtin_amdgcn_mfma_f32_16x16x32_bf16(a1, bw, acc[1][tn], 0, 0, 0);
            }
        }
        __syncthreads();   // drains vmcnt (prefetch landed) + all waves done reading cur/A-chunk
        buf ^= 1;
    }

    // all MFMAs complete across the block (last __syncthreads) -> safe in-place writeback
    #pragma unroll
    for (int tn = 0; tn < TN; ++tn) {
        const int col = col0 + tn * 16 + lrow;
        const float bias = Bg[col];
        #pragma unroll
        for (int tm = 0; tm < 2; ++tm) {
            #pragma unroll
            for (int j = 0; j < 4; ++j) {
                float v = acc[tm][tn][j] + bias;
                if (RELU) v = fmaxf(v, 0.f);
                const int row = row0 + tm * 16 + (lane >> 4) * 4 + j;
                *(ushort*)(sA + swA(row, col * 2)) = f2bf(v);
            }
        }
    }
    __syncthreads();
}

// ---------------------------------------------------------------------------
// Fused: taps + PE MLP + gather-add + encoder MLP + softmax + output
// ---------------------------------------------------------------------------
template <bool USE_WS>
__global__ __launch_bounds__(1024, 1) void fused_kernel(
    const float* __restrict__ depth, const float* __restrict__ feat,
    const float* __restrict__ coord,
    const float* __restrict__ pb0, const float* __restrict__ pb1,
    const float* __restrict__ pb2,
    const float* __restrict__ eb0, const float* __restrict__ eb1,
    const float* __restrict__ eb2,
    const float* __restrict__ ew3, const float* __restrict__ eb3,
    const ushort* __restrict__ wt,
    const ushort* __restrict__ nhwc, const float* __restrict__ xyws,
    float* __restrict__ out)
{
    extern __shared__ char lds[];
    char*  sA   = lds + OFF_A;
    int*   sTap = (int*)(lds + OFF_TAP);
    float* sPxy = (float*)(lds + OFF_PXY);
    float* sE3  = (float*)(lds + OFF_E3);

    const int tid  = threadIdx.x;
    const int lane = tid & 63, wv = tid >> 6;
    const int row0g = blockIdx.x * ROWS;
    const int b     = row0g >> 17;   // QQ = 2^17, ROWS | QQ

    int buf = 0;

    // prologue: prefetch pe0 chunk 0 into buf 0 (overlaps setup VALU)
    {
        const char* src = (const char*)(wt + WOFF_PE0);   // 8192 B
        for (int u = wv; u < 8; u += 16)
            gload_lds16(src + (size_t)u * 1024 + lane * 16, lds + OFF_W + u * 1024);
    }

    // stage final-layer weights (64x4 f32)
    if (tid < 256) sE3[tid] = ew3[tid];

    // zero A cols 0..63 (pe0 K padded 8->64); swizzle permutes within bytes 0..127
    {
        const int r = tid >> 3, c16 = tid & 7;
        uint4 z; z.x = z.y = z.z = z.w = 0u;
        *(uint4*)(sA + r * ASTR_B + c16 * 16) = z;
    }
    __syncthreads();

    // taps + rel coords + pred_xy; fp32, contraction OFF (match numpy rounding)
    if (tid < 512) {
        #pragma clang fp contract(off)
        const int r = tid >> 2, s = tid & 3;
        const int row = row0g + r;
        const float cy = coord[row * 2 + 0];
        const float cx = coord[row * 2 + 1];
        const float offy = (s < 2) ? -1.f : 1.f;
        const float offx = (s & 1) ? 1.f : -1.f;
        const float rx = 1.f / (float)HH, ry = 1.f / (float)WWID;
        float ccy = cy + (offy * rx + 1e-6f);
        float ccx = cx + (offx * ry + 1e-6f);
        ccy = fminf(fmaxf(ccy, -1.f + 1e-6f), 1.f - 1e-6f);
        ccx = fminf(fmaxf(ccx, -1.f + 1e-6f), 1.f - 1e-6f);
        int iy = (int)rintf(((ccy + 1.f) * (float)HH - 1.f) * 0.5f);
        int ix = (int)rintf(((ccx + 1.f) * (float)WWID - 1.f) * 0.5f);
        iy = min(max(iy, 0), HH - 1);
        ix = min(max(ix, 0), WWID - 1);
        const float qcy = -1.f + (2.f * (float)iy + 1.f) / (float)HH;
        const float qcx = -1.f + (2.f * (float)ix + 1.f) / (float)WWID;
        *(ushort*)(sA + swA(r, s * 4 + 0)) = f2bf((cy - qcy) * (float)HH);
        *(ushort*)(sA + swA(r, s * 4 + 2)) = f2bf((cx - qcx) * (float)WWID);
        const int tap = iy * WWID + ix;
        sTap[r * 4 + s] = tap;
        float px;
        if (USE_WS) {
            px = xyws[b * HWSZ + tap];
        } else {
            const float d1 = depth[(b * 3 + 1) * HWSZ + tap];
            const float d2 = depth[(b * 3 + 2) * HWSZ + tap];
            px = sqrtf(d1 * d1 + d2 * d2);
        }
        sPxy[r * 4 + s] = px;
    }
    __syncthreads();

    // PE MLP (rel coords in A cols 0..7, zero-padded to 64)
    dense_layer<64,  64,  true >(lds, buf, wt + WOFF_PE0, pb0, wt + WOFF_PE1, 128*128, tid);
    dense_layer<64,  128, true >(lds, buf, wt + WOFF_PE1, pb1, wt + WOFF_PE2, 256*128, tid);
    dense_layer<128, 256, false>(lds, buf, wt + WOFF_PE2, pb2, wt + WOFF_E0,  256*128, tid);

    // gather-add q_feat: A[r][s*64+c] += feat[b,c,tap]
    {
        const int r = tid >> 3, h = tid & 7;
        const int s = h >> 1, half = h & 1;
        const int tap = sTap[r * 4 + s];
        const int cb0 = s * 128 + half * 64;   // byte offset of 32 channels
        if (USE_WS) {
            const ushort* src = nhwc + ((size_t)b * HWSZ + tap) * CC + half * 32;
            #pragma unroll
            for (int g = 0; g < 4; ++g) {
                char* dp = sA + swA(r, cb0 + g * 16);
                union { uint4 v; ushort u[8]; } a, d, o;
                a.v = *(const uint4*)(src + g * 8);
                d.v = *(uint4*)dp;
                #pragma unroll
                for (int j = 0; j < 8; ++j)
                    o.u[j] = f2bf(bf2f(a.u[j]) + bf2f(d.u[j]));
                *(uint4*)dp = o.v;
            }
        } else {
            const float* fp = feat + (size_t)b * CC * HWSZ + tap;
            #pragma unroll 8
            for (int c = 0; c < 32; ++c) {
                const int ch = half * 32 + c;
                ushort* p = (ushort*)(sA + swA(r, cb0 + c * 2));
                *p = f2bf(bf2f(*p) + fp[(size_t)ch * HWSZ]);
            }
        }
    }
    __syncthreads();

    // encoder MLP
    dense_layer<256, 256, true>(lds, buf, wt + WOFF_E0, eb0, wt + WOFF_E1, 128*128, tid);
    dense_layer<256, 128, true>(lds, buf, wt + WOFF_E1, eb1, wt + WOFF_E2, 64*128, tid);
    dense_layer<128, 64,  true>(lds, buf, wt + WOFF_E2, eb2, nullptr, 0, tid);

    // final 64->4, softmax, weighted sum with pred_xy (4 threads per row)
    if (tid < 512) {
        const int r = tid >> 2, sub = tid & 3;
        float l0 = 0.f, l1 = 0.f, l2 = 0.f, l3 = 0.f;
        #pragma unroll
        for (int kk = 0; kk < 16; ++kk) {
            const int k = sub * 16 + kk;
            const float a = bf2f(*(const ushort*)(sA + swA(r, k * 2)));
            const float4 w = ((const float4*)sE3)[k];
            l0 = fmaf(a, w.x, l0);
            l1 = fmaf(a, w.y, l1);
            l2 = fmaf(a, w.z, l2);
            l3 = fmaf(a, w.w, l3);
        }
        #pragma unroll
        for (int m = 1; m <= 2; m <<= 1) {
            l0 += __shfl_xor(l0, m);
            l1 += __shfl_xor(l1, m);
            l2 += __shfl_xor(l2, m);
            l3 += __shfl_xor(l3, m);
        }
        if (sub == 0) {
            l0 += eb3[0]; l1 += eb3[1]; l2 += eb3[2]; l3 += eb3[3];
            const float m  = fmaxf(fmaxf(l0, l1), fmaxf(l2, l3));
            const float e0 = expf(l0 - m), e1 = expf(l1 - m);
            const float e2 = expf(l2 - m), e3 = expf(l3 - m);
            const float inv = 1.f / (e0 + e1 + e2 + e3);
            const float o = (sPxy[r * 4 + 0] * e0 + sPxy[r * 4 + 1] * e1 +
                             sPxy[r * 4 + 2] * e2 + sPxy[r * 4 + 3] * e3) * inv;
            out[row0g + r] = o;
        }
    }
}

// ---------------------------------------------------------------------------
extern "C" void kernel_launch(void* const* d_in, const int* in_sizes, int n_in,
                              void* d_out, int out_size, void* d_ws, size_t ws_size,
                              hipStream_t stream)
{
    const float* depth = (const float*)d_in[0];
    const float* feat  = (const float*)d_in[1];
    const float* coord = (const float*)d_in[2];
    const float* pw0 = (const float*)d_in[3],  *pb0 = (const float*)d_in[4];
    const float* pw1 = (const float*)d_in[5],  *pb1 = (const float*)d_in[6];
    const float* pw2 = (const float*)d_in[7],  *pb2 = (const float*)d_in[8];
    const float* ew0 = (const float*)d_in[9],  *eb0 = (const float*)d_in[10];
    const float* ew1 = (const float*)d_in[11], *eb1 = (const float*)d_in[12];
    const float* ew2 = (const float*)d_in[13], *eb2 = (const float*)d_in[14];
    const float* ew3 = (const float*)d_in[15], *eb3 = (const float*)d_in[16];
    float* out = (float*)d_out;

    const size_t nhwc_bytes = (size_t)NBATCH * HWSZ * CC * 2;
    const size_t xy_bytes   = (size_t)NBATCH * HWSZ * 4;
    const size_t wt_bytes   = (size_t)WTOTAL * 2;
    const bool use_ws = (ws_size >= nhwc_bytes + xy_bytes + wt_bytes);

    ushort* nhwc = (ushort*)d_ws;
    float*  xyws = (float*)((char*)d_ws + nhwc_bytes);
    ushort* wt   = use_ws ? (ushort*)((char*)d_ws + nhwc_bytes + xy_bytes)
                          : (ushort*)d_ws;

    WPack pack;
    pack.d[0] = { pw0, 8,   64,  6 };
    pack.d[1] = { pw1, 64,  128, 6 };
    pack.d[2] = { pw2, 128, 256, 7 };
    pack.d[3] = { ew0, 256, 256, 8 };
    pack.d[4] = { ew1, 256, 128, 8 };
    pack.d[5] = { ew2, 128, 64,  7 };
    prep_weights<<<WTOTAL / 256, 256, 0, stream>>>(pack, wt);

    const int nblocks = (NBATCH * QQ) / ROWS;   // 2048

    if (use_ws) {
        prep_feat<<<(NBATCH * HWSZ) / 256, 256, 0, stream>>>(depth, feat, nhwc, xyws);
        hipFuncSetAttribute((const void*)fused_kernel<true>,
                            hipFuncAttributeMaxDynamicSharedMemorySize, LDS_BYTES);
        fused_kernel<true><<<nblocks, THREADS, LDS_BYTES, stream>>>(
            depth, feat, coord, pb0, pb1, pb2, eb0, eb1, eb2, ew3, eb3,
            wt, nhwc, xyws, out);
    } else {
        hipFuncSetAttribute((const void*)fused_kernel<false>,
                            hipFuncAttributeMaxDynamicSharedMemorySize, LDS_BYTES);
        fused_kernel<false><<<nblocks, THREADS, LDS_BYTES, stream>>>(
            depth, feat, coord, pb0, pb1, pb2, eb0, eb1, eb2, ew3, eb3,
            wt, nhwc, xyws, out);
    }
}

// Round 4
// 339.385 us; speedup vs baseline: 1.0078x; 1.0078x over previous
//
#include <hip/hip_runtime.h>
#include <hip/hip_runtime_api.h>
#include <math.h>

#define NBATCH 2
#define QQ     131072
#define HH     64
#define WWID   2048
#define CC     64
#define HWSZ   (HH*WWID)   /* 131072 = 2^17 */

constexpr int ROWS    = 128;   // rows per block
constexpr int THREADS = 1024;  // 16 waves, 4M x 4N wave grid

// A: 128 rows x 512 B (256 bf16), XOR-swizzled; byte ^= (row&7)<<4
constexpr int ASTR_B = 512;

// dynamic-LDS byte offsets
constexpr int WBUF    = 32768;             // one W chunk buffer (max: N=256,K=64)
constexpr int OFF_A   = 0;                 // 65536 B
constexpr int OFF_W   = 65536;             // 2 x 32768 B
constexpr int OFF_TAP = OFF_W + 2*WBUF;    // tap[128][4] int  = 2048 B
constexpr int OFF_PXY = OFF_TAP + 2048;    // pxy[128][4] f32  = 2048 B
constexpr int OFF_E3  = OFF_PXY + 2048;    // ew3 64x4 f32     = 1024 B
constexpr int LDS_BYTES = OFF_E3 + 1024;   // 136192 B -> 1 block/CU, 16 waves

// packed fragment-layout weight offsets in elements (Kp = K padded to 64)
constexpr int WOFF_PE0 = 0;       // N=64,  Kp=64   -> 4096
constexpr int WOFF_PE1 = 4096;    // N=128, Kp=64   -> 8192
constexpr int WOFF_PE2 = 12288;   // N=256, Kp=128  -> 32768
constexpr int WOFF_E0  = 45056;   // N=256, Kp=256  -> 65536
constexpr int WOFF_E1  = 110592;  // N=128, Kp=256  -> 32768
constexpr int WOFF_E2  = 143360;  // N=64,  Kp=128  -> 8192
constexpr int WTOTAL   = 151552;

typedef __attribute__((ext_vector_type(8))) short bf16x8;
typedef __attribute__((ext_vector_type(4))) float f32x4;

__device__ __forceinline__ ushort f2bf(float f) {
    union { float f; unsigned u; } x; x.f = f;
    unsigned r = x.u + 0x7fffu + ((x.u >> 16) & 1u);   // RNE
    return (ushort)(r >> 16);
}
__device__ __forceinline__ float bf2f(ushort h) {
    union { unsigned u; float f; } x; x.u = ((unsigned)h) << 16;
    return x.f;
}

// swizzled A byte address (colByte may be 2-byte granular; XOR flips bits 4-6)
__device__ __forceinline__ int swA(int row, int colByte) {
    return row * ASTR_B + (colByte ^ ((row & 7) << 4));
}

// async global->LDS, 16 B per lane (dst = wave-uniform base + lane*16)
__device__ __forceinline__ void gload_lds16(const void* g, void* l) {
    __builtin_amdgcn_global_load_lds(
        (const __attribute__((address_space(1))) unsigned int*)g,
        (__attribute__((address_space(3))) unsigned int*)l, 16, 0, 0);
}

// ---------------------------------------------------------------------------
// Weight prep: fp32 [K][N] -> bf16 MFMA-fragment-packed [chunks][tiles][512]
// tile = 16 cols x 32 k, lane-ordered: elem(lane,j) = W[k0+(lane>>4)*8+j][n0+(lane&15)]
// chunk = 64 k-wide: tiles ordered (n>>4)*2 + kk
// ---------------------------------------------------------------------------
struct WDesc { const float* src; int K; int N; int kshift; };  // Kp = 1<<kshift
struct WPack { WDesc d[6]; };

__global__ __launch_bounds__(256) void prep_weights(WPack p, ushort* __restrict__ dst)
{
    int e = blockIdx.x * 256 + threadIdx.x;
    int off = 0;
    #pragma unroll
    for (int L = 0; L < 6; ++L) {
        const int Kp = 1 << p.d[L].kshift;
        const int N  = p.d[L].N;
        const int sz = N * Kp;
        if (e < sz) {
            const int n = e / Kp;
            const int k = e & (Kp - 1);
            const float v = (k < p.d[L].K) ? p.d[L].src[(size_t)k * N + n] : 0.f;
            const int chunk = k >> 6;
            const int kk    = (k >> 5) & 1;
            const int tile  = chunk * ((N >> 4) * 2) + (n >> 4) * 2 + kk;
            const int lane  = (n & 15) + (((k >> 3) & 3) << 4);
            const int j     = k & 7;
            dst[off + tile * 512 + lane * 8 + j] = f2bf(v);
            return;
        }
        e -= sz; off += sz;
    }
}

// ---------------------------------------------------------------------------
// Feat prep: NCHW f32 -> NHWC bf16, plus xy = sqrt(d1^2+d2^2)
// ---------------------------------------------------------------------------
__global__ __launch_bounds__(256) void prep_feat(
    const float* __restrict__ depth, const float* __restrict__ feat,
    ushort* __restrict__ nhwc, float* __restrict__ xy)
{
    const int idx = blockIdx.x * 256 + threadIdx.x;
    const int b   = idx >> 17;
    const int yx  = idx & (HWSZ - 1);

    const float d1 = depth[(b * 3 + 1) * HWSZ + yx];
    const float d2 = depth[(b * 3 + 2) * HWSZ + yx];
    xy[idx] = sqrtf(d1 * d1 + d2 * d2);

    const float* fp = feat + (size_t)b * CC * HWSZ + yx;
    ushort* op = nhwc + (size_t)idx * CC;
    #pragma unroll
    for (int c = 0; c < CC; c += 8) {
        union { uint4 v; ushort u[8]; } t;
        #pragma unroll
        for (int j = 0; j < 8; ++j) t.u[j] = f2bf(fp[(size_t)(c + j) * HWSZ]);
        *(uint4*)(op + c) = t.v;
    }
}

// ---------------------------------------------------------------------------
// One dense layer, in place on A (bf16, swizzled LDS). 16 waves = 4M x 4N.
// Wave tile 32 rows x N/4 cols, 16x16x32 MFMA. W double-buffered in LDS via
// global_load_lds with one-chunk-ahead prefetch (incl. next layer's chunk 0).
// ---------------------------------------------------------------------------
template <int K, int N, bool RELU>
__device__ __forceinline__ void dense_layer(
    char* __restrict__ lds, int& buf,
    const ushort* __restrict__ Wt, const float* __restrict__ Bg,
    const ushort* __restrict__ nextWt, int nextBytes, int tid)
{
    constexpr int TN  = N / 64;        // 16-col tiles per wave
    constexpr int NCH = K / 64;        // 64-wide K chunks
    constexpr int CHB = N * 128;       // bytes per chunk

    char* sA = lds + OFF_A;
    const int lane = tid & 63, wv = tid >> 6;
    const int wm = wv >> 2, wn = wv & 3;
    const int row0 = wm * 32;
    const int col0 = wn * (N / 4);
    const int lrow = lane & 15;
    const int lkb  = (lane >> 4) * 16;   // byte offset of this lane's 8 bf16 in k

    f32x4 acc[2][TN];
    #pragma unroll
    for (int tm = 0; tm < 2; ++tm)
        #pragma unroll
        for (int tn = 0; tn < TN; ++tn) acc[tm][tn] = (f32x4){0.f, 0.f, 0.f, 0.f};

    #pragma unroll
    for (int c = 0; c < NCH; ++c) {
        char* cur = lds + OFF_W + buf * WBUF;
        char* nxt = lds + OFF_W + (buf ^ 1) * WBUF;

        // prefetch next chunk (or next layer's chunk 0) into nxt
        const char* src = (c + 1 < NCH) ? (const char*)Wt + (size_t)(c + 1) * CHB
                                        : (const char*)nextWt;
        const int nb = (c + 1 < NCH) ? CHB : nextBytes;
        for (int u = wv; u * 1024 < nb; u += 16)
            gload_lds16(src + (size_t)u * 1024 + lane * 16, nxt + u * 1024);

        // compute on cur (resident: waited before previous barrier)
        #pragma unroll
        for (int ks = 0; ks < 64; ks += 32) {
            const int cb = (c * 64 + ks) * 2 + lkb;
            const bf16x8 a0 = *(const bf16x8*)(sA + swA(row0 +      lrow, cb));
            const bf16x8 a1 = *(const bf16x8*)(sA + swA(row0 + 16 + lrow, cb));
            #pragma unroll
            for (int tn = 0; tn < TN; ++tn) {
                const int tile = (wn * (N >> 6) + tn) * 2 + (ks >> 5);
                const bf16x8 bw = *(const bf16x8*)(cur + tile * 1024 + lane * 16);
                acc[0][tn] = __builtin_amdgcn_mfma_f32_16x16x32_bf16(a0, bw, acc[0][tn], 0, 0, 0);
                acc[1][tn] = __builtin_amdgcn_mfma_f32_16x16x32_bf16(a1, bw, acc[1][tn], 0, 0, 0);
            }
        }
        __syncthreads();   // drains vmcnt (prefetch landed) + all waves done reading cur/A-chunk
        buf ^= 1;
    }

    // all MFMAs complete across the block (last __syncthreads) -> safe in-place writeback
    #pragma unroll
    for (int tn = 0; tn < TN; ++tn) {
        const int col = col0 + tn * 16 + lrow;
        const float bias = Bg[col];
        #pragma unroll
        for (int tm = 0; tm < 2; ++tm) {
            #pragma unroll
            for (int j = 0; j < 4; ++j) {
                float v = acc[tm][tn][j] + bias;
                if (RELU) v = fmaxf(v, 0.f);
                const int row = row0 + tm * 16 + (lane >> 4) * 4 + j;
                *(ushort*)(sA + swA(row, col * 2)) = f2bf(v);
            }
        }
    }
    __syncthreads();
}

// ---------------------------------------------------------------------------
// Fused: taps + PE MLP + gather-add + encoder MLP + softmax + output
// __launch_bounds__(1024, 4): 16-wave block, 4 waves/EU = 1 block/CU ->
// 128-VGPR budget (round 3's (1024,1) degenerated to a 64-VGPR cap -> scratch
// spills -> the 449 MB WRITE_SIZE and the regression).
// ---------------------------------------------------------------------------
template <bool USE_WS>
__global__ __launch_bounds__(1024, 4) void fused_kernel(
    const float* __restrict__ depth, const float* __restrict__ feat,
    const float* __restrict__ coord,
    const float* __restrict__ pb0, const float* __restrict__ pb1,
    const float* __restrict__ pb2,
    const float* __restrict__ eb0, const float* __restrict__ eb1,
    const float* __restrict__ eb2,
    const float* __restrict__ ew3, const float* __restrict__ eb3,
    const ushort* __restrict__ wt,
    const ushort* __restrict__ nhwc, const float* __restrict__ xyws,
    float* __restrict__ out)
{
    extern __shared__ char lds[];
    char*  sA   = lds + OFF_A;
    int*   sTap = (int*)(lds + OFF_TAP);
    float* sPxy = (float*)(lds + OFF_PXY);
    float* sE3  = (float*)(lds + OFF_E3);

    const int tid  = threadIdx.x;
    const int lane = tid & 63, wv = tid >> 6;
    const int row0g = blockIdx.x * ROWS;
    const int b     = row0g >> 17;   // QQ = 2^17, ROWS | QQ

    int buf = 0;

    // prologue: prefetch pe0 chunk 0 into buf 0 (overlaps setup VALU)
    {
        const char* src = (const char*)(wt + WOFF_PE0);   // 8192 B
        for (int u = wv; u < 8; u += 16)
            gload_lds16(src + (size_t)u * 1024 + lane * 16, lds + OFF_W + u * 1024);
    }

    // stage final-layer weights (64x4 f32)
    if (tid < 256) sE3[tid] = ew3[tid];

    // zero A cols 0..63 (pe0 K padded 8->64); swizzle permutes within bytes 0..127
    {
        const int r = tid >> 3, c16 = tid & 7;
        uint4 z; z.x = z.y = z.z = z.w = 0u;
        *(uint4*)(sA + r * ASTR_B + c16 * 16) = z;
    }
    __syncthreads();

    // taps + rel coords + pred_xy; fp32, contraction OFF (match numpy rounding)
    if (tid < 512) {
        #pragma clang fp contract(off)
        const int r = tid >> 2, s = tid & 3;
        const int row = row0g + r;
        const float cy = coord[row * 2 + 0];
        const float cx = coord[row * 2 + 1];
        const float offy = (s < 2) ? -1.f : 1.f;
        const float offx = (s & 1) ? 1.f : -1.f;
        const float rx = 1.f / (float)HH, ry = 1.f / (float)WWID;
        float ccy = cy + (offy * rx + 1e-6f);
        float ccx = cx + (offx * ry + 1e-6f);
        ccy = fminf(fmaxf(ccy, -1.f + 1e-6f), 1.f - 1e-6f);
        ccx = fminf(fmaxf(ccx, -1.f + 1e-6f), 1.f - 1e-6f);
        int iy = (int)rintf(((ccy + 1.f) * (float)HH - 1.f) * 0.5f);
        int ix = (int)rintf(((ccx + 1.f) * (float)WWID - 1.f) * 0.5f);
        iy = min(max(iy, 0), HH - 1);
        ix = min(max(ix, 0), WWID - 1);
        const float qcy = -1.f + (2.f * (float)iy + 1.f) / (float)HH;
        const float qcx = -1.f + (2.f * (float)ix + 1.f) / (float)WWID;
        *(ushort*)(sA + swA(r, s * 4 + 0)) = f2bf((cy - qcy) * (float)HH);
        *(ushort*)(sA + swA(r, s * 4 + 2)) = f2bf((cx - qcx) * (float)WWID);
        const int tap = iy * WWID + ix;
        sTap[r * 4 + s] = tap;
        float px;
        if (USE_WS) {
            px = xyws[b * HWSZ + tap];
        } else {
            const float d1 = depth[(b * 3 + 1) * HWSZ + tap];
            const float d2 = depth[(b * 3 + 2) * HWSZ + tap];
            px = sqrtf(d1 * d1 + d2 * d2);
        }
        sPxy[r * 4 + s] = px;
    }
    __syncthreads();

    // PE MLP (rel coords in A cols 0..7, zero-padded to 64)
    dense_layer<64,  64,  true >(lds, buf, wt + WOFF_PE0, pb0, wt + WOFF_PE1, 128*128, tid);
    dense_layer<64,  128, true >(lds, buf, wt + WOFF_PE1, pb1, wt + WOFF_PE2, 256*128, tid);
    dense_layer<128, 256, false>(lds, buf, wt + WOFF_PE2, pb2, wt + WOFF_E0,  256*128, tid);

    // gather-add q_feat: A[r][s*64+c] += feat[b,c,tap]
    {
        const int r = tid >> 3, h = tid & 7;
        const int s = h >> 1, half = h & 1;
        const int tap = sTap[r * 4 + s];
        const int cb0 = s * 128 + half * 64;   // byte offset of 32 channels
        if (USE_WS) {
            const ushort* src = nhwc + ((size_t)b * HWSZ + tap) * CC + half * 32;
            #pragma unroll
            for (int g = 0; g < 4; ++g) {
                char* dp = sA + swA(r, cb0 + g * 16);
                union { uint4 v; ushort u[8]; } a, d, o;
                a.v = *(const uint4*)(src + g * 8);
                d.v = *(uint4*)dp;
                #pragma unroll
                for (int j = 0; j < 8; ++j)
                    o.u[j] = f2bf(bf2f(a.u[j]) + bf2f(d.u[j]));
                *(uint4*)dp = o.v;
            }
        } else {
            const float* fp = feat + (size_t)b * CC * HWSZ + tap;
            #pragma unroll 8
            for (int c = 0; c < 32; ++c) {
                const int ch = half * 32 + c;
                ushort* p = (ushort*)(sA + swA(r, cb0 + c * 2));
                *p = f2bf(bf2f(*p) + fp[(size_t)ch * HWSZ]);
            }
        }
    }
    __syncthreads();

    // encoder MLP
    dense_layer<256, 256, true>(lds, buf, wt + WOFF_E0, eb0, wt + WOFF_E1, 128*128, tid);
    dense_layer<256, 128, true>(lds, buf, wt + WOFF_E1, eb1, wt + WOFF_E2, 64*128, tid);
    dense_layer<128, 64,  true>(lds, buf, wt + WOFF_E2, eb2, nullptr, 0, tid);

    // final 64->4, softmax, weighted sum with pred_xy (4 threads per row)
    if (tid < 512) {
        const int r = tid >> 2, sub = tid & 3;
        float l0 = 0.f, l1 = 0.f, l2 = 0.f, l3 = 0.f;
        #pragma unroll
        for (int kk = 0; kk < 16; ++kk) {
            const int k = sub * 16 + kk;
            const float a = bf2f(*(const ushort*)(sA + swA(r, k * 2)));
            const float4 w = ((const float4*)sE3)[k];
            l0 = fmaf(a, w.x, l0);
            l1 = fmaf(a, w.y, l1);
            l2 = fmaf(a, w.z, l2);
            l3 = fmaf(a, w.w, l3);
        }
        #pragma unroll
        for (int m = 1; m <= 2; m <<= 1) {
            l0 += __shfl_xor(l0, m);
            l1 += __shfl_xor(l1, m);
            l2 += __shfl_xor(l2, m);
            l3 += __shfl_xor(l3, m);
        }
        if (sub == 0) {
            l0 += eb3[0]; l1 += eb3[1]; l2 += eb3[2]; l3 += eb3[3];
            const float m  = fmaxf(fmaxf(l0, l1), fmaxf(l2, l3));
            const float e0 = expf(l0 - m), e1 = expf(l1 - m);
            const float e2 = expf(l2 - m), e3 = expf(l3 - m);
            const float inv = 1.f / (e0 + e1 + e2 + e3);
            const float o = (sPxy[r * 4 + 0] * e0 + sPxy[r * 4 + 1] * e1 +
                             sPxy[r * 4 + 2] * e2 + sPxy[r * 4 + 3] * e3) * inv;
            out[row0g + r] = o;
        }
    }
}

// ---------------------------------------------------------------------------
extern "C" void kernel_launch(void* const* d_in, const int* in_sizes, int n_in,
                              void* d_out, int out_size, void* d_ws, size_t ws_size,
                              hipStream_t stream)
{
    const float* depth = (const float*)d_in[0];
    const float* feat  = (const float*)d_in[1];
    const float* coord = (const float*)d_in[2];
    const float* pw0 = (const float*)d_in[3],  *pb0 = (const float*)d_in[4];
    const float* pw1 = (const float*)d_in[5],  *pb1 = (const float*)d_in[6];
    const float* pw2 = (const float*)d_in[7],  *pb2 = (const float*)d_in[8];
    const float* ew0 = (const float*)d_in[9],  *eb0 = (const float*)d_in[10];
    const float* ew1 = (const float*)d_in[11], *eb1 = (const float*)d_in[12];
    const float* ew2 = (const float*)d_in[13], *eb2 = (const float*)d_in[14];
    const float* ew3 = (const float*)d_in[15], *eb3 = (const float*)d_in[16];
    float* out = (float*)d_out;

    const size_t nhwc_bytes = (size_t)NBATCH * HWSZ * CC * 2;
    const size_t xy_bytes   = (size_t)NBATCH * HWSZ * 4;
    const size_t wt_bytes   = (size_t)WTOTAL * 2;
    const bool use_ws = (ws_size >= nhwc_bytes + xy_bytes + wt_bytes);

    ushort* nhwc = (ushort*)d_ws;
    float*  xyws = (float*)((char*)d_ws + nhwc_bytes);
    ushort* wt   = use_ws ? (ushort*)((char*)d_ws + nhwc_bytes + xy_bytes)
                          : (ushort*)d_ws;

    WPack pack;
    pack.d[0] = { pw0, 8,   64,  6 };
    pack.d[1] = { pw1, 64,  128, 6 };
    pack.d[2] = { pw2, 128, 256, 7 };
    pack.d[3] = { ew0, 256, 256, 8 };
    pack.d[4] = { ew1, 256, 128, 8 };
    pack.d[5] = { ew2, 128, 64,  7 };
    prep_weights<<<WTOTAL / 256, 256, 0, stream>>>(pack, wt);

    const int nblocks = (NBATCH * QQ) / ROWS;   // 2048

    if (use_ws) {
        prep_feat<<<(NBATCH * HWSZ) / 256, 256, 0, stream>>>(depth, feat, nhwc, xyws);
        hipFuncSetAttribute((const void*)fused_kernel<true>,
                            hipFuncAttributeMaxDynamicSharedMemorySize, LDS_BYTES);
        fused_kernel<true><<<nblocks, THREADS, LDS_BYTES, stream>>>(
            depth, feat, coord, pb0, pb1, pb2, eb0, eb1, eb2, ew3, eb3,
            wt, nhwc, xyws, out);
    } else {
        hipFuncSetAttribute((const void*)fused_kernel<false>,
                            hipFuncAttributeMaxDynamicSharedMemorySize, LDS_BYTES);
        fused_kernel<false><<<nblocks, THREADS, LDS_BYTES, stream>>>(
            depth, feat, coord, pb0, pb1, pb2, eb0, eb1, eb2, ew3, eb3,
            wt, nhwc, xyws, out);
    }
}

// Round 5
// 335.895 us; speedup vs baseline: 1.0182x; 1.0104x over previous
//
#include <hip/hip_runtime.h>
#include <hip/hip_runtime_api.h>
#include <math.h>

#define NBATCH 2
#define QQ     131072
#define HH     64
#define WWID   2048
#define CC     64
#define HWSZ   (HH*WWID)   /* 131072 = 2^17 */

constexpr int ROWS    = 128;   // rows per block
constexpr int THREADS = 1024;  // 16 waves, 4M x 4N wave grid

// A: 128 rows x 512 B (256 bf16), XOR-swizzled; byte ^= (row&7)<<4
constexpr int ASTR_B = 512;

// dynamic-LDS byte offsets
constexpr int WBUF    = 32768;             // one W chunk buffer (max: N=256,K=64)
constexpr int OFF_A   = 0;                 // 65536 B
constexpr int OFF_W   = 65536;             // 2 x 32768 B
constexpr int OFF_TAP = OFF_W + 2*WBUF;    // tap[128][4] int  = 2048 B
constexpr int OFF_PXY = OFF_TAP + 2048;    // pxy[128][4] f32  = 2048 B
constexpr int OFF_E3  = OFF_PXY + 2048;    // ew3 64x4 f32     = 1024 B
constexpr int LDS_BYTES = OFF_E3 + 1024;   // 136192 B -> 1 block/CU, 16 waves

// packed fragment-layout weight offsets in elements (Kp = K padded to 64)
constexpr int WOFF_PE0 = 0;       // N=64,  Kp=64   -> 4096
constexpr int WOFF_PE1 = 4096;    // N=128, Kp=64   -> 8192
constexpr int WOFF_PE2 = 12288;   // N=256, Kp=128  -> 32768
constexpr int WOFF_E0  = 45056;   // N=256, Kp=256  -> 65536
constexpr int WOFF_E1  = 110592;  // N=128, Kp=256  -> 32768
constexpr int WOFF_E2  = 143360;  // N=64,  Kp=128  -> 8192
constexpr int WTOTAL   = 151552;

typedef __attribute__((ext_vector_type(8))) short bf16x8;
typedef __attribute__((ext_vector_type(4))) float f32x4;

__device__ __forceinline__ ushort f2bf(float f) {
    union { float f; unsigned u; } x; x.f = f;
    unsigned r = x.u + 0x7fffu + ((x.u >> 16) & 1u);   // RNE
    return (ushort)(r >> 16);
}
__device__ __forceinline__ float bf2f(ushort h) {
    union { unsigned u; float f; } x; x.u = ((unsigned)h) << 16;
    return x.f;
}

// swizzled A byte address (colByte may be 2-byte granular; XOR flips bits 4-6)
__device__ __forceinline__ int swA(int row, int colByte) {
    return row * ASTR_B + (colByte ^ ((row & 7) << 4));
}

// async global->LDS, 16 B per lane (dst = wave-uniform base + lane*16)
__device__ __forceinline__ void gload_lds16(const void* g, void* l) {
    __builtin_amdgcn_global_load_lds(
        (const __attribute__((address_space(1))) unsigned int*)g,
        (__attribute__((address_space(3))) unsigned int*)l, 16, 0, 0);
}

// ---------------------------------------------------------------------------
// Weight prep: fp32 [K][N] -> bf16 MFMA-fragment-packed [chunks][tiles][512]
// tile = 16 cols x 32 k, lane-ordered: elem(lane,j) = W[k0+(lane>>4)*8+j][n0+(lane&15)]
// chunk = 64 k-wide: tiles ordered (n>>4)*2 + kk
// ---------------------------------------------------------------------------
struct WDesc { const float* src; int K; int N; int kshift; };  // Kp = 1<<kshift
struct WPack { WDesc d[6]; };

__global__ __launch_bounds__(256) void prep_weights(WPack p, ushort* __restrict__ dst)
{
    int e = blockIdx.x * 256 + threadIdx.x;
    int off = 0;
    #pragma unroll
    for (int L = 0; L < 6; ++L) {
        const int Kp = 1 << p.d[L].kshift;
        const int N  = p.d[L].N;
        const int sz = N * Kp;
        if (e < sz) {
            const int n = e / Kp;
            const int k = e & (Kp - 1);
            const float v = (k < p.d[L].K) ? p.d[L].src[(size_t)k * N + n] : 0.f;
            const int chunk = k >> 6;
            const int kk    = (k >> 5) & 1;
            const int tile  = chunk * ((N >> 4) * 2) + (n >> 4) * 2 + kk;
            const int lane  = (n & 15) + (((k >> 3) & 3) << 4);
            const int j     = k & 7;
            dst[off + tile * 512 + lane * 8 + j] = f2bf(v);
            return;
        }
        e -= sz; off += sz;
    }
}

// ---------------------------------------------------------------------------
// Feat prep: NCHW f32 -> NHWC bf16, plus xy = sqrt(d1^2+d2^2)
// ---------------------------------------------------------------------------
__global__ __launch_bounds__(256) void prep_feat(
    const float* __restrict__ depth, const float* __restrict__ feat,
    ushort* __restrict__ nhwc, float* __restrict__ xy)
{
    const int idx = blockIdx.x * 256 + threadIdx.x;
    const int b   = idx >> 17;
    const int yx  = idx & (HWSZ - 1);

    const float d1 = depth[(b * 3 + 1) * HWSZ + yx];
    const float d2 = depth[(b * 3 + 2) * HWSZ + yx];
    xy[idx] = sqrtf(d1 * d1 + d2 * d2);

    const float* fp = feat + (size_t)b * CC * HWSZ + yx;
    ushort* op = nhwc + (size_t)idx * CC;
    #pragma unroll
    for (int c = 0; c < CC; c += 8) {
        union { uint4 v; ushort u[8]; } t;
        #pragma unroll
        for (int j = 0; j < 8; ++j) t.u[j] = f2bf(fp[(size_t)(c + j) * HWSZ]);
        *(uint4*)(op + c) = t.v;
    }
}

// ---------------------------------------------------------------------------
// One dense layer, in place on A (bf16, swizzled LDS). 16 waves = 4M x 4N.
// Wave tile 32 rows x N/4 cols, 16x16x32 MFMA. W double-buffered in LDS via
// global_load_lds with one-chunk-ahead prefetch (incl. next layer's chunk 0).
// ---------------------------------------------------------------------------
template <int K, int N, bool RELU>
__device__ __forceinline__ void dense_layer(
    char* __restrict__ lds, int& buf,
    const ushort* __restrict__ Wt, const float* __restrict__ Bg,
    const ushort* __restrict__ nextWt, int nextBytes, int tid)
{
    constexpr int TN  = N / 64;        // 16-col tiles per wave
    constexpr int NCH = K / 64;        // 64-wide K chunks
    constexpr int CHB = N * 128;       // bytes per chunk

    char* sA = lds + OFF_A;
    const int lane = tid & 63, wv = tid >> 6;
    const int wm = wv >> 2, wn = wv & 3;
    const int row0 = wm * 32;
    const int col0 = wn * (N / 4);
    const int lrow = lane & 15;
    const int lkb  = (lane >> 4) * 16;   // byte offset of this lane's 8 bf16 in k

    f32x4 acc[2][TN];
    #pragma unroll
    for (int tm = 0; tm < 2; ++tm)
        #pragma unroll
        for (int tn = 0; tn < TN; ++tn) acc[tm][tn] = (f32x4){0.f, 0.f, 0.f, 0.f};

    #pragma unroll
    for (int c = 0; c < NCH; ++c) {
        char* cur = lds + OFF_W + buf * WBUF;
        char* nxt = lds + OFF_W + (buf ^ 1) * WBUF;

        // prefetch next chunk (or next layer's chunk 0) into nxt
        const char* src = (c + 1 < NCH) ? (const char*)Wt + (size_t)(c + 1) * CHB
                                        : (const char*)nextWt;
        const int nb = (c + 1 < NCH) ? CHB : nextBytes;
        for (int u = wv; u * 1024 < nb; u += 16)
            gload_lds16(src + (size_t)u * 1024 + lane * 16, nxt + u * 1024);

        // compute on cur (resident: waited before previous barrier)
        #pragma unroll
        for (int ks = 0; ks < 64; ks += 32) {
            const int cb = (c * 64 + ks) * 2 + lkb;
            const bf16x8 a0 = *(const bf16x8*)(sA + swA(row0 +      lrow, cb));
            const bf16x8 a1 = *(const bf16x8*)(sA + swA(row0 + 16 + lrow, cb));
            #pragma unroll
            for (int tn = 0; tn < TN; ++tn) {
                const int tile = (wn * (N >> 6) + tn) * 2 + (ks >> 5);
                const bf16x8 bw = *(const bf16x8*)(cur + tile * 1024 + lane * 16);
                acc[0][tn] = __builtin_amdgcn_mfma_f32_16x16x32_bf16(a0, bw, acc[0][tn], 0, 0, 0);
                acc[1][tn] = __builtin_amdgcn_mfma_f32_16x16x32_bf16(a1, bw, acc[1][tn], 0, 0, 0);
            }
        }
        __syncthreads();   // drains vmcnt (prefetch landed) + all waves done reading cur/A-chunk
        buf ^= 1;
    }

    // all MFMAs complete across the block (last __syncthreads) -> safe in-place writeback
    #pragma unroll
    for (int tn = 0; tn < TN; ++tn) {
        const int col = col0 + tn * 16 + lrow;
        const float bias = Bg[col];
        #pragma unroll
        for (int tm = 0; tm < 2; ++tm) {
            #pragma unroll
            for (int j = 0; j < 4; ++j) {
                float v = acc[tm][tn][j] + bias;
                if (RELU) v = fmaxf(v, 0.f);
                const int row = row0 + tm * 16 + (lane >> 4) * 4 + j;
                *(ushort*)(sA + swA(row, col * 2)) = f2bf(v);
            }
        }
    }
    __syncthreads();
}

// ---------------------------------------------------------------------------
// Fused: taps + PE MLP + gather-add + encoder MLP + softmax + output
// amdgpu_waves_per_eu(4,4): pin regalloc to exactly 4 waves/EU (1 block/CU,
// which the 136 KB LDS forces anyway) -> 128-VGPR budget. launch_bounds(1024,4)
// was a no-op (4/EU is already the minimum for a 16-wave block), so the
// allocator kept a 64-VGPR budget and spilled ~450 MB/dispatch to scratch.
// ---------------------------------------------------------------------------
template <bool USE_WS>
__global__ __attribute__((amdgpu_flat_work_group_size(1024, 1024),
                          amdgpu_waves_per_eu(4, 4)))
void fused_kernel(
    const float* __restrict__ depth, const float* __restrict__ feat,
    const float* __restrict__ coord,
    const float* __restrict__ pb0, const float* __restrict__ pb1,
    const float* __restrict__ pb2,
    const float* __restrict__ eb0, const float* __restrict__ eb1,
    const float* __restrict__ eb2,
    const float* __restrict__ ew3, const float* __restrict__ eb3,
    const ushort* __restrict__ wt,
    const ushort* __restrict__ nhwc, const float* __restrict__ xyws,
    float* __restrict__ out)
{
    extern __shared__ char lds[];
    char*  sA   = lds + OFF_A;
    int*   sTap = (int*)(lds + OFF_TAP);
    float* sPxy = (float*)(lds + OFF_PXY);
    float* sE3  = (float*)(lds + OFF_E3);

    const int tid  = threadIdx.x;
    const int lane = tid & 63, wv = tid >> 6;
    const int row0g = blockIdx.x * ROWS;
    const int b     = row0g >> 17;   // QQ = 2^17, ROWS | QQ

    int buf = 0;

    // prologue: prefetch pe0 chunk 0 into buf 0 (overlaps setup VALU)
    {
        const char* src = (const char*)(wt + WOFF_PE0);   // 8192 B
        for (int u = wv; u < 8; u += 16)
            gload_lds16(src + (size_t)u * 1024 + lane * 16, lds + OFF_W + u * 1024);
    }

    // stage final-layer weights (64x4 f32)
    if (tid < 256) sE3[tid] = ew3[tid];

    // zero A cols 0..63 (pe0 K padded 8->64); swizzle permutes within bytes 0..127
    {
        const int r = tid >> 3, c16 = tid & 7;
        uint4 z; z.x = z.y = z.z = z.w = 0u;
        *(uint4*)(sA + r * ASTR_B + c16 * 16) = z;
    }
    __syncthreads();

    // taps + rel coords + pred_xy; fp32, contraction OFF (match numpy rounding)
    if (tid < 512) {
        #pragma clang fp contract(off)
        const int r = tid >> 2, s = tid & 3;
        const int row = row0g + r;
        const float cy = coord[row * 2 + 0];
        const float cx = coord[row * 2 + 1];
        const float offy = (s < 2) ? -1.f : 1.f;
        const float offx = (s & 1) ? 1.f : -1.f;
        const float rx = 1.f / (float)HH, ry = 1.f / (float)WWID;
        float ccy = cy + (offy * rx + 1e-6f);
        float ccx = cx + (offx * ry + 1e-6f);
        ccy = fminf(fmaxf(ccy, -1.f + 1e-6f), 1.f - 1e-6f);
        ccx = fminf(fmaxf(ccx, -1.f + 1e-6f), 1.f - 1e-6f);
        int iy = (int)rintf(((ccy + 1.f) * (float)HH - 1.f) * 0.5f);
        int ix = (int)rintf(((ccx + 1.f) * (float)WWID - 1.f) * 0.5f);
        iy = min(max(iy, 0), HH - 1);
        ix = min(max(ix, 0), WWID - 1);
        const float qcy = -1.f + (2.f * (float)iy + 1.f) / (float)HH;
        const float qcx = -1.f + (2.f * (float)ix + 1.f) / (float)WWID;
        *(ushort*)(sA + swA(r, s * 4 + 0)) = f2bf((cy - qcy) * (float)HH);
        *(ushort*)(sA + swA(r, s * 4 + 2)) = f2bf((cx - qcx) * (float)WWID);
        const int tap = iy * WWID + ix;
        sTap[r * 4 + s] = tap;
        float px;
        if (USE_WS) {
            px = xyws[b * HWSZ + tap];
        } else {
            const float d1 = depth[(b * 3 + 1) * HWSZ + tap];
            const float d2 = depth[(b * 3 + 2) * HWSZ + tap];
            px = sqrtf(d1 * d1 + d2 * d2);
        }
        sPxy[r * 4 + s] = px;
    }
    __syncthreads();

    // PE MLP (rel coords in A cols 0..7, zero-padded to 64)
    dense_layer<64,  64,  true >(lds, buf, wt + WOFF_PE0, pb0, wt + WOFF_PE1, 128*128, tid);
    dense_layer<64,  128, true >(lds, buf, wt + WOFF_PE1, pb1, wt + WOFF_PE2, 256*128, tid);
    dense_layer<128, 256, false>(lds, buf, wt + WOFF_PE2, pb2, wt + WOFF_E0,  256*128, tid);

    // gather-add q_feat: A[r][s*64+c] += feat[b,c,tap]
    {
        const int r = tid >> 3, h = tid & 7;
        const int s = h >> 1, half = h & 1;
        const int tap = sTap[r * 4 + s];
        const int cb0 = s * 128 + half * 64;   // byte offset of 32 channels
        if (USE_WS) {
            const ushort* src = nhwc + ((size_t)b * HWSZ + tap) * CC + half * 32;
            #pragma unroll
            for (int g = 0; g < 4; ++g) {
                char* dp = sA + swA(r, cb0 + g * 16);
                union { uint4 v; ushort u[8]; } a, d, o;
                a.v = *(const uint4*)(src + g * 8);
                d.v = *(uint4*)dp;
                #pragma unroll
                for (int j = 0; j < 8; ++j)
                    o.u[j] = f2bf(bf2f(a.u[j]) + bf2f(d.u[j]));
                *(uint4*)dp = o.v;
            }
        } else {
            const float* fp = feat + (size_t)b * CC * HWSZ + tap;
            #pragma unroll 8
            for (int c = 0; c < 32; ++c) {
                const int ch = half * 32 + c;
                ushort* p = (ushort*)(sA + swA(r, cb0 + c * 2));
                *p = f2bf(bf2f(*p) + fp[(size_t)ch * HWSZ]);
            }
        }
    }
    __syncthreads();

    // encoder MLP
    dense_layer<256, 256, true>(lds, buf, wt + WOFF_E0, eb0, wt + WOFF_E1, 128*128, tid);
    dense_layer<256, 128, true>(lds, buf, wt + WOFF_E1, eb1, wt + WOFF_E2, 64*128, tid);
    dense_layer<128, 64,  true>(lds, buf, wt + WOFF_E2, eb2, nullptr, 0, tid);

    // final 64->4, softmax, weighted sum with pred_xy (4 threads per row)
    if (tid < 512) {
        const int r = tid >> 2, sub = tid & 3;
        float l0 = 0.f, l1 = 0.f, l2 = 0.f, l3 = 0.f;
        #pragma unroll
        for (int kk = 0; kk < 16; ++kk) {
            const int k = sub * 16 + kk;
            const float a = bf2f(*(const ushort*)(sA + swA(r, k * 2)));
            const float4 w = ((const float4*)sE3)[k];
            l0 = fmaf(a, w.x, l0);
            l1 = fmaf(a, w.y, l1);
            l2 = fmaf(a, w.z, l2);
            l3 = fmaf(a, w.w, l3);
        }
        #pragma unroll
        for (int m = 1; m <= 2; m <<= 1) {
            l0 += __shfl_xor(l0, m);
            l1 += __shfl_xor(l1, m);
            l2 += __shfl_xor(l2, m);
            l3 += __shfl_xor(l3, m);
        }
        if (sub == 0) {
            l0 += eb3[0]; l1 += eb3[1]; l2 += eb3[2]; l3 += eb3[3];
            const float m  = fmaxf(fmaxf(l0, l1), fmaxf(l2, l3));
            const float e0 = expf(l0 - m), e1 = expf(l1 - m);
            const float e2 = expf(l2 - m), e3 = expf(l3 - m);
            const float inv = 1.f / (e0 + e1 + e2 + e3);
            const float o = (sPxy[r * 4 + 0] * e0 + sPxy[r * 4 + 1] * e1 +
                             sPxy[r * 4 + 2] * e2 + sPxy[r * 4 + 3] * e3) * inv;
            out[row0g + r] = o;
        }
    }
}

// ---------------------------------------------------------------------------
extern "C" void kernel_launch(void* const* d_in, const int* in_sizes, int n_in,
                              void* d_out, int out_size, void* d_ws, size_t ws_size,
                              hipStream_t stream)
{
    const float* depth = (const float*)d_in[0];
    const float* feat  = (const float*)d_in[1];
    const float* coord = (const float*)d_in[2];
    const float* pw0 = (const float*)d_in[3],  *pb0 = (const float*)d_in[4];
    const float* pw1 = (const float*)d_in[5],  *pb1 = (const float*)d_in[6];
    const float* pw2 = (const float*)d_in[7],  *pb2 = (const float*)d_in[8];
    const float* ew0 = (const float*)d_in[9],  *eb0 = (const float*)d_in[10];
    const float* ew1 = (const float*)d_in[11], *eb1 = (const float*)d_in[12];
    const float* ew2 = (const float*)d_in[13], *eb2 = (const float*)d_in[14];
    const float* ew3 = (const float*)d_in[15], *eb3 = (const float*)d_in[16];
    float* out = (float*)d_out;

    const size_t nhwc_bytes = (size_t)NBATCH * HWSZ * CC * 2;
    const size_t xy_bytes   = (size_t)NBATCH * HWSZ * 4;
    const size_t wt_bytes   = (size_t)WTOTAL * 2;
    const bool use_ws = (ws_size >= nhwc_bytes + xy_bytes + wt_bytes);

    ushort* nhwc = (ushort*)d_ws;
    float*  xyws = (float*)((char*)d_ws + nhwc_bytes);
    ushort* wt   = use_ws ? (ushort*)((char*)d_ws + nhwc_bytes + xy_bytes)
                          : (ushort*)d_ws;

    WPack pack;
    pack.d[0] = { pw0, 8,   64,  6 };
    pack.d[1] = { pw1, 64,  128, 6 };
    pack.d[2] = { pw2, 128, 256, 7 };
    pack.d[3] = { ew0, 256, 256, 8 };
    pack.d[4] = { ew1, 256, 128, 8 };
    pack.d[5] = { ew2, 128, 64,  7 };
    prep_weights<<<WTOTAL / 256, 256, 0, stream>>>(pack, wt);

    const int nblocks = (NBATCH * QQ) / ROWS;   // 2048

    if (use_ws) {
        prep_feat<<<(NBATCH * HWSZ) / 256, 256, 0, stream>>>(depth, feat, nhwc, xyws);
        hipFuncSetAttribute((const void*)fused_kernel<true>,
                            hipFuncAttributeMaxDynamicSharedMemorySize, LDS_BYTES);
        fused_kernel<true><<<nblocks, THREADS, LDS_BYTES, stream>>>(
            depth, feat, coord, pb0, pb1, pb2, eb0, eb1, eb2, ew3, eb3,
            wt, nhwc, xyws, out);
    } else {
        hipFuncSetAttribute((const void*)fused_kernel<false>,
                            hipFuncAttributeMaxDynamicSharedMemorySize, LDS_BYTES);
        fused_kernel<false><<<nblocks, THREADS, LDS_BYTES, stream>>>(
            depth, feat, coord, pb0, pb1, pb2, eb0, eb1, eb2, ew3, eb3,
            wt, nhwc, xyws, out);
    }
}

// Round 6
// 225.865 us; speedup vs baseline: 1.5143x; 1.4872x over previous
//
#include <hip/hip_runtime.h>
#include <hip/hip_runtime_api.h>
#include <math.h>

#define NBATCH 2
#define QQ     131072
#define HH     64
#define WWID   2048
#define CC     64
#define HWSZ   (HH*WWID)   /* 131072 = 2^17 */

constexpr int ROWS    = 128;   // rows per block
constexpr int THREADS = 1024;  // 16 waves, 4M x 4N wave grid

// A: 128 rows x 512 B (256 bf16), XOR-swizzled; byte ^= (row&7)<<4
constexpr int ASTR_B = 512;

// dynamic-LDS byte offsets (no W staging anymore: B-frags come global->VGPR)
constexpr int OFF_A   = 0;                 // 65536 B
constexpr int OFF_TAP = 65536;             // tap[128][4] int  = 2048 B
constexpr int OFF_PXY = OFF_TAP + 2048;    // pxy[128][4] f32  = 2048 B
constexpr int OFF_E3  = OFF_PXY + 2048;    // ew3 64x4 f32     = 1024 B
constexpr int LDS_BYTES = OFF_E3 + 1024;   // 70656 B -> 2 blocks/CU, 32 waves/CU

// packed fragment-layout weight offsets in elements (Kp = K padded to 64)
constexpr int WOFF_PE0 = 0;       // N=64,  Kp=64   -> 4096
constexpr int WOFF_PE1 = 4096;    // N=128, Kp=64   -> 8192
constexpr int WOFF_PE2 = 12288;   // N=256, Kp=128  -> 32768
constexpr int WOFF_E0  = 45056;   // N=256, Kp=256  -> 65536
constexpr int WOFF_E1  = 110592;  // N=128, Kp=256  -> 32768
constexpr int WOFF_E2  = 143360;  // N=64,  Kp=128  -> 8192
constexpr int WTOTAL   = 151552;

typedef __attribute__((ext_vector_type(8))) short bf16x8;
typedef __attribute__((ext_vector_type(4))) float f32x4;

__device__ __forceinline__ ushort f2bf(float f) {
    union { float f; unsigned u; } x; x.f = f;
    unsigned r = x.u + 0x7fffu + ((x.u >> 16) & 1u);   // RNE
    return (ushort)(r >> 16);
}
__device__ __forceinline__ float bf2f(ushort h) {
    union { unsigned u; float f; } x; x.u = ((unsigned)h) << 16;
    return x.f;
}

// swizzled A byte address (XOR flips bits 4-6 by row)
__device__ __forceinline__ int swA(int row, int colByte) {
    return row * ASTR_B + (colByte ^ ((row & 7) << 4));
}

// ---------------------------------------------------------------------------
// Weight prep: fp32 [K][N] -> bf16 MFMA-fragment-packed [chunks][tiles][512]
// tile = 16 cols x 32 k, lane-ordered: elem(lane,j) = W[k0+(lane>>4)*8+j][n0+(lane&15)]
// chunk = 64 k-wide: tiles ordered (n>>4)*2 + kk
// ---------------------------------------------------------------------------
struct WDesc { const float* src; int K; int N; int kshift; };  // Kp = 1<<kshift
struct WPack { WDesc d[6]; };

__global__ __launch_bounds__(256) void prep_weights(WPack p, ushort* __restrict__ dst)
{
    int e = blockIdx.x * 256 + threadIdx.x;
    int off = 0;
    #pragma unroll
    for (int L = 0; L < 6; ++L) {
        const int Kp = 1 << p.d[L].kshift;
        const int N  = p.d[L].N;
        const int sz = N * Kp;
        if (e < sz) {
            const int n = e / Kp;
            const int k = e & (Kp - 1);
            const float v = (k < p.d[L].K) ? p.d[L].src[(size_t)k * N + n] : 0.f;
            const int chunk = k >> 6;
            const int kk    = (k >> 5) & 1;
            const int tile  = chunk * ((N >> 4) * 2) + (n >> 4) * 2 + kk;
            const int lane  = (n & 15) + (((k >> 3) & 3) << 4);
            const int j     = k & 7;
            dst[off + tile * 512 + lane * 8 + j] = f2bf(v);
            return;
        }
        e -= sz; off += sz;
    }
}

// ---------------------------------------------------------------------------
// Feat prep: NCHW f32 -> NHWC bf16, plus xy = sqrt(d1^2+d2^2)
// ---------------------------------------------------------------------------
__global__ __launch_bounds__(256) void prep_feat(
    const float* __restrict__ depth, const float* __restrict__ feat,
    ushort* __restrict__ nhwc, float* __restrict__ xy)
{
    const int idx = blockIdx.x * 256 + threadIdx.x;
    const int b   = idx >> 17;
    const int yx  = idx & (HWSZ - 1);

    const float d1 = depth[(b * 3 + 1) * HWSZ + yx];
    const float d2 = depth[(b * 3 + 2) * HWSZ + yx];
    xy[idx] = sqrtf(d1 * d1 + d2 * d2);

    const float* fp = feat + (size_t)b * CC * HWSZ + yx;
    ushort* op = nhwc + (size_t)idx * CC;
    #pragma unroll
    for (int c = 0; c < CC; c += 8) {
        union { uint4 v; ushort u[8]; } t;
        #pragma unroll
        for (int j = 0; j < 8; ++j) t.u[j] = f2bf(fp[(size_t)(c + j) * HWSZ]);
        *(uint4*)(op + c) = t.v;
    }
}

// ---------------------------------------------------------------------------
// One dense layer, in place on A (bf16, swizzled LDS). 16 waves = 4M x 4N.
// Wave tile 32 rows x N/4 cols, 16x16x32 MFMA. B-fragments loaded DIRECTLY
// global->VGPR from fragment-packed wt (1 KB coalesced per wave-load; 4 waves
// share each tile -> L1/L2-hot). No W staging, no per-chunk barriers.
// ---------------------------------------------------------------------------
template <int K, int N, bool RELU>
__device__ __forceinline__ void dense_layer(
    char* __restrict__ sA, const ushort* __restrict__ Wt,
    const float* __restrict__ Bg, int tid)
{
    constexpr int TN  = N / 64;        // 16-col tiles per wave
    constexpr int NCH = K / 64;        // 64-wide K chunks

    const int lane = tid & 63, wv = tid >> 6;
    const int wm = wv >> 2, wn = wv & 3;
    const int row0 = wm * 32;
    const int col0 = wn * (N / 4);
    const int lrow = lane & 15;
    const int lkb  = (lane >> 4) * 16;   // byte offset of this lane's 8 bf16 in k

    f32x4 acc[2][TN];
    #pragma unroll
    for (int tm = 0; tm < 2; ++tm)
        #pragma unroll
        for (int tn = 0; tn < TN; ++tn) acc[tm][tn] = (f32x4){0.f, 0.f, 0.f, 0.f};

    const char* wbase = (const char*)Wt + (size_t)lane * 16;

    for (int c = 0; c < NCH; ++c) {
        #pragma unroll
        for (int ks = 0; ks < 64; ks += 32) {
            const int cb = (c * 64 + ks) * 2 + lkb;
            const bf16x8 a0 = *(const bf16x8*)(sA + swA(row0 +      lrow, cb));
            const bf16x8 a1 = *(const bf16x8*)(sA + swA(row0 + 16 + lrow, cb));
            #pragma unroll
            for (int tn = 0; tn < TN; ++tn) {
                const int tile = c * ((N >> 4) * 2) + ((col0 >> 4) + tn) * 2 + (ks >> 5);
                const bf16x8 bw = *(const bf16x8*)(wbase + tile * 1024);
                acc[0][tn] = __builtin_amdgcn_mfma_f32_16x16x32_bf16(a0, bw, acc[0][tn], 0, 0, 0);
                acc[1][tn] = __builtin_amdgcn_mfma_f32_16x16x32_bf16(a1, bw, acc[1][tn], 0, 0, 0);
            }
        }
    }
    __syncthreads();   // all waves done reading A -> safe in-place writeback

    #pragma unroll
    for (int tn = 0; tn < TN; ++tn) {
        const int col = col0 + tn * 16 + lrow;
        const float bias = Bg[col];
        #pragma unroll
        for (int tm = 0; tm < 2; ++tm) {
            #pragma unroll
            for (int j = 0; j < 4; ++j) {
                float v = acc[tm][tn][j] + bias;
                if (RELU) v = fmaxf(v, 0.f);
                const int row = row0 + tm * 16 + (lane >> 4) * 4 + j;
                *(ushort*)(sA + swA(row, col * 2)) = f2bf(v);
            }
        }
    }
    __syncthreads();
}

// ---------------------------------------------------------------------------
// Fused: taps + PE MLP + gather-add + encoder MLP + softmax + output
// ---------------------------------------------------------------------------
template <bool USE_WS>
__global__ __launch_bounds__(1024) void fused_kernel(
    const float* __restrict__ depth, const float* __restrict__ feat,
    const float* __restrict__ coord,
    const float* __restrict__ pb0, const float* __restrict__ pb1,
    const float* __restrict__ pb2,
    const float* __restrict__ eb0, const float* __restrict__ eb1,
    const float* __restrict__ eb2,
    const float* __restrict__ ew3, const float* __restrict__ eb3,
    const ushort* __restrict__ wt,
    const ushort* __restrict__ nhwc, const float* __restrict__ xyws,
    float* __restrict__ out)
{
    extern __shared__ char lds[];
    char*  sA   = lds + OFF_A;
    int*   sTap = (int*)(lds + OFF_TAP);
    float* sPxy = (float*)(lds + OFF_PXY);
    float* sE3  = (float*)(lds + OFF_E3);

    const int tid  = threadIdx.x;
    const int row0g = blockIdx.x * ROWS;
    const int b     = row0g >> 17;   // QQ = 2^17, ROWS | QQ

    // stage final-layer weights (64x4 f32)
    if (tid < 256) sE3[tid] = ew3[tid];

    // zero A cols 0..63 (pe0 K padded 8->64); swizzle permutes within bytes 0..127
    {
        const int r = tid >> 3, c16 = tid & 7;
        uint4 z; z.x = z.y = z.z = z.w = 0u;
        *(uint4*)(sA + r * ASTR_B + c16 * 16) = z;
    }
    __syncthreads();

    // taps + rel coords + pred_xy; fp32, contraction OFF (match numpy rounding)
    if (tid < 512) {
        #pragma clang fp contract(off)
        const int r = tid >> 2, s = tid & 3;
        const int row = row0g + r;
        const float cy = coord[row * 2 + 0];
        const float cx = coord[row * 2 + 1];
        const float offy = (s < 2) ? -1.f : 1.f;
        const float offx = (s & 1) ? 1.f : -1.f;
        const float rx = 1.f / (float)HH, ry = 1.f / (float)WWID;
        float ccy = cy + (offy * rx + 1e-6f);
        float ccx = cx + (offx * ry + 1e-6f);
        ccy = fminf(fmaxf(ccy, -1.f + 1e-6f), 1.f - 1e-6f);
        ccx = fminf(fmaxf(ccx, -1.f + 1e-6f), 1.f - 1e-6f);
        int iy = (int)rintf(((ccy + 1.f) * (float)HH - 1.f) * 0.5f);
        int ix = (int)rintf(((ccx + 1.f) * (float)WWID - 1.f) * 0.5f);
        iy = min(max(iy, 0), HH - 1);
        ix = min(max(ix, 0), WWID - 1);
        const float qcy = -1.f + (2.f * (float)iy + 1.f) / (float)HH;
        const float qcx = -1.f + (2.f * (float)ix + 1.f) / (float)WWID;
        *(ushort*)(sA + swA(r, s * 4 + 0)) = f2bf((cy - qcy) * (float)HH);
        *(ushort*)(sA + swA(r, s * 4 + 2)) = f2bf((cx - qcx) * (float)WWID);
        const int tap = iy * WWID + ix;
        sTap[r * 4 + s] = tap;
        float px;
        if (USE_WS) {
            px = xyws[b * HWSZ + tap];
        } else {
            const float d1 = depth[(b * 3 + 1) * HWSZ + tap];
            const float d2 = depth[(b * 3 + 2) * HWSZ + tap];
            px = sqrtf(d1 * d1 + d2 * d2);
        }
        sPxy[r * 4 + s] = px;
    }
    __syncthreads();

    // PE MLP (rel coords in A cols 0..7, zero-padded to 64)
    dense_layer<64,  64,  true >(sA, wt + WOFF_PE0, pb0, tid);
    dense_layer<64,  128, true >(sA, wt + WOFF_PE1, pb1, tid);
    dense_layer<128, 256, false>(sA, wt + WOFF_PE2, pb2, tid);

    // gather-add q_feat: A[r][s*64+c] += feat[b,c,tap]
    {
        const int r = tid >> 3, h = tid & 7;
        const int s = h >> 1, half = h & 1;
        const int tap = sTap[r * 4 + s];
        const int cb0 = s * 128 + half * 64;   // byte offset of 32 channels
        if (USE_WS) {
            const ushort* src = nhwc + ((size_t)b * HWSZ + tap) * CC + half * 32;
            #pragma unroll
            for (int g = 0; g < 4; ++g) {
                char* dp = sA + swA(r, cb0 + g * 16);
                union { uint4 v; ushort u[8]; } a, d, o;
                a.v = *(const uint4*)(src + g * 8);
                d.v = *(uint4*)dp;
                #pragma unroll
                for (int j = 0; j < 8; ++j)
                    o.u[j] = f2bf(bf2f(a.u[j]) + bf2f(d.u[j]));
                *(uint4*)dp = o.v;
            }
        } else {
            const float* fp = feat + (size_t)b * CC * HWSZ + tap;
            #pragma unroll 8
            for (int c = 0; c < 32; ++c) {
                const int ch = half * 32 + c;
                ushort* p = (ushort*)(sA + swA(r, cb0 + c * 2));
                *p = f2bf(bf2f(*p) + fp[(size_t)ch * HWSZ]);
            }
        }
    }
    __syncthreads();

    // encoder MLP
    dense_layer<256, 256, true>(sA, wt + WOFF_E0, eb0, tid);
    dense_layer<256, 128, true>(sA, wt + WOFF_E1, eb1, tid);
    dense_layer<128, 64,  true>(sA, wt + WOFF_E2, eb2, tid);

    // final 64->4, softmax, weighted sum with pred_xy (4 threads per row)
    if (tid < 512) {
        const int r = tid >> 2, sub = tid & 3;
        float l0 = 0.f, l1 = 0.f, l2 = 0.f, l3 = 0.f;
        #pragma unroll
        for (int kk = 0; kk < 16; ++kk) {
            const int k = sub * 16 + kk;
            const float a = bf2f(*(const ushort*)(sA + swA(r, k * 2)));
            const float4 w = ((const float4*)sE3)[k];
            l0 = fmaf(a, w.x, l0);
            l1 = fmaf(a, w.y, l1);
            l2 = fmaf(a, w.z, l2);
            l3 = fmaf(a, w.w, l3);
        }
        #pragma unroll
        for (int m = 1; m <= 2; m <<= 1) {
            l0 += __shfl_xor(l0, m);
            l1 += __shfl_xor(l1, m);
            l2 += __shfl_xor(l2, m);
            l3 += __shfl_xor(l3, m);
        }
        if (sub == 0) {
            l0 += eb3[0]; l1 += eb3[1]; l2 += eb3[2]; l3 += eb3[3];
            const float m  = fmaxf(fmaxf(l0, l1), fmaxf(l2, l3));
            const float e0 = expf(l0 - m), e1 = expf(l1 - m);
            const float e2 = expf(l2 - m), e3 = expf(l3 - m);
            const float inv = 1.f / (e0 + e1 + e2 + e3);
            const float o = (sPxy[r * 4 + 0] * e0 + sPxy[r * 4 + 1] * e1 +
                             sPxy[r * 4 + 2] * e2 + sPxy[r * 4 + 3] * e3) * inv;
            out[row0g + r] = o;
        }
    }
}

// ---------------------------------------------------------------------------
extern "C" void kernel_launch(void* const* d_in, const int* in_sizes, int n_in,
                              void* d_out, int out_size, void* d_ws, size_t ws_size,
                              hipStream_t stream)
{
    const float* depth = (const float*)d_in[0];
    const float* feat  = (const float*)d_in[1];
    const float* coord = (const float*)d_in[2];
    const float* pw0 = (const float*)d_in[3],  *pb0 = (const float*)d_in[4];
    const float* pw1 = (const float*)d_in[5],  *pb1 = (const float*)d_in[6];
    const float* pw2 = (const float*)d_in[7],  *pb2 = (const float*)d_in[8];
    const float* ew0 = (const float*)d_in[9],  *eb0 = (const float*)d_in[10];
    const float* ew1 = (const float*)d_in[11], *eb1 = (const float*)d_in[12];
    const float* ew2 = (const float*)d_in[13], *eb2 = (const float*)d_in[14];
    const float* ew3 = (const float*)d_in[15], *eb3 = (const float*)d_in[16];
    float* out = (float*)d_out;

    const size_t nhwc_bytes = (size_t)NBATCH * HWSZ * CC * 2;
    const size_t xy_bytes   = (size_t)NBATCH * HWSZ * 4;
    const size_t wt_bytes   = (size_t)WTOTAL * 2;
    const bool use_ws = (ws_size >= nhwc_bytes + xy_bytes + wt_bytes);

    ushort* nhwc = (ushort*)d_ws;
    float*  xyws = (float*)((char*)d_ws + nhwc_bytes);
    ushort* wt   = use_ws ? (ushort*)((char*)d_ws + nhwc_bytes + xy_bytes)
                          : (ushort*)d_ws;

    WPack pack;
    pack.d[0] = { pw0, 8,   64,  6 };
    pack.d[1] = { pw1, 64,  128, 6 };
    pack.d[2] = { pw2, 128, 256, 7 };
    pack.d[3] = { ew0, 256, 256, 8 };
    pack.d[4] = { ew1, 256, 128, 8 };
    pack.d[5] = { ew2, 128, 64,  7 };
    prep_weights<<<WTOTAL / 256, 256, 0, stream>>>(pack, wt);

    const int nblocks = (NBATCH * QQ) / ROWS;   // 2048

    if (use_ws) {
        prep_feat<<<(NBATCH * HWSZ) / 256, 256, 0, stream>>>(depth, feat, nhwc, xyws);
        hipFuncSetAttribute((const void*)fused_kernel<true>,
                            hipFuncAttributeMaxDynamicSharedMemorySize, LDS_BYTES);
        fused_kernel<true><<<nblocks, THREADS, LDS_BYTES, stream>>>(
            depth, feat, coord, pb0, pb1, pb2, eb0, eb1, eb2, ew3, eb3,
            wt, nhwc, xyws, out);
    } else {
        hipFuncSetAttribute((const void*)fused_kernel<false>,
                            hipFuncAttributeMaxDynamicSharedMemorySize, LDS_BYTES);
        fused_kernel<false><<<nblocks, THREADS, LDS_BYTES, stream>>>(
            depth, feat, coord, pb0, pb1, pb2, eb0, eb1, eb2, ew3, eb3,
            wt, nhwc, xyws, out);
    }
}

// Round 7
// 215.729 us; speedup vs baseline: 1.5854x; 1.0470x over previous
//
#include <hip/hip_runtime.h>
#include <hip/hip_runtime_api.h>
#include <math.h>

#define NBATCH 2
#define QQ     131072
#define HH     64
#define WWID   2048
#define CC     64
#define HWSZ   (HH*WWID)   /* 131072 = 2^17 */

constexpr int ROWS    = 64;    // rows per block
constexpr int THREADS = 512;   // 8 waves, 2M x 4N wave grid

// A: 64 rows x 512 B (256 bf16), XOR-swizzled; byte ^= (row&7)<<4
constexpr int ASTR_B = 512;

// dynamic-LDS byte offsets
constexpr int OFF_A   = 0;                 // 32768 B
constexpr int OFF_TAP = 32768;             // tap[64][4] int  = 1024 B
constexpr int OFF_PXY = OFF_TAP + 1024;    // pxy[64][4] f32  = 1024 B
constexpr int OFF_E3  = OFF_PXY + 1024;    // ew3 64x4 f32    = 1024 B
constexpr int LDS_BYTES = OFF_E3 + 1024;   // 35840 B -> 4 blocks/CU, 32 waves/CU

// packed fragment-layout weight offsets in elements (Kp = K padded to 64)
constexpr int WOFF_PE0 = 0;       // N=64,  Kp=64   -> 4096
constexpr int WOFF_PE1 = 4096;    // N=128, Kp=64   -> 8192
constexpr int WOFF_PE2 = 12288;   // N=256, Kp=128  -> 32768
constexpr int WOFF_E0  = 45056;   // N=256, Kp=256  -> 65536
constexpr int WOFF_E1  = 110592;  // N=128, Kp=256  -> 32768
constexpr int WOFF_E2  = 143360;  // N=64,  Kp=128  -> 8192
constexpr int WTOTAL   = 151552;

typedef __attribute__((ext_vector_type(8))) short bf16x8;
typedef __attribute__((ext_vector_type(4))) float f32x4;

__device__ __forceinline__ ushort f2bf(float f) {
    union { float f; unsigned u; } x; x.f = f;
    unsigned r = x.u + 0x7fffu + ((x.u >> 16) & 1u);   // RNE
    return (ushort)(r >> 16);
}
__device__ __forceinline__ float bf2f(ushort h) {
    union { unsigned u; float f; } x; x.u = ((unsigned)h) << 16;
    return x.f;
}
// pack 2 f32 -> 2 bf16 in one u32 (RNE, gfx950). lo = cvt(a), hi = cvt(b).
__device__ __forceinline__ unsigned cvtpk(float a, float b) {
    unsigned r;
    asm("v_cvt_pk_bf16_f32 %0, %1, %2" : "=v"(r) : "v"(a), "v"(b));
    return r;
}

// swizzled A byte address (XOR flips bits 4-6 by row)
__device__ __forceinline__ int swA(int row, int colByte) {
    return row * ASTR_B + (colByte ^ ((row & 7) << 4));
}

// ---------------------------------------------------------------------------
// Weight prep: fp32 [K][N] -> bf16 MFMA-fragment-packed [chunks][tiles][512]
// tile = 16 cols x 32 k, lane-ordered: elem(lane,j) = W[k0+(lane>>4)*8+j][n0+(lane&15)]
// chunk = 64 k-wide: tiles ordered (n>>4)*2 + kk
// ---------------------------------------------------------------------------
struct WDesc { const float* src; int K; int N; int kshift; };  // Kp = 1<<kshift
struct WPack { WDesc d[6]; };

__global__ __launch_bounds__(256) void prep_weights(WPack p, ushort* __restrict__ dst)
{
    int e = blockIdx.x * 256 + threadIdx.x;
    int off = 0;
    #pragma unroll
    for (int L = 0; L < 6; ++L) {
        const int Kp = 1 << p.d[L].kshift;
        const int N  = p.d[L].N;
        const int sz = N * Kp;
        if (e < sz) {
            const int n = e / Kp;
            const int k = e & (Kp - 1);
            const float v = (k < p.d[L].K) ? p.d[L].src[(size_t)k * N + n] : 0.f;
            const int chunk = k >> 6;
            const int kk    = (k >> 5) & 1;
            const int tile  = chunk * ((N >> 4) * 2) + (n >> 4) * 2 + kk;
            const int lane  = (n & 15) + (((k >> 3) & 3) << 4);
            const int j     = k & 7;
            dst[off + tile * 512 + lane * 8 + j] = f2bf(v);
            return;
        }
        e -= sz; off += sz;
    }
}

// ---------------------------------------------------------------------------
// Feat prep: NCHW f32 -> NHWC bf16, plus xy = sqrt(d1^2+d2^2)
// ---------------------------------------------------------------------------
__global__ __launch_bounds__(256) void prep_feat(
    const float* __restrict__ depth, const float* __restrict__ feat,
    ushort* __restrict__ nhwc, float* __restrict__ xy)
{
    const int idx = blockIdx.x * 256 + threadIdx.x;
    const int b   = idx >> 17;
    const int yx  = idx & (HWSZ - 1);

    const float d1 = depth[(b * 3 + 1) * HWSZ + yx];
    const float d2 = depth[(b * 3 + 2) * HWSZ + yx];
    xy[idx] = sqrtf(d1 * d1 + d2 * d2);

    const float* fp = feat + (size_t)b * CC * HWSZ + yx;
    ushort* op = nhwc + (size_t)idx * CC;
    #pragma unroll
    for (int c = 0; c < CC; c += 8) {
        union { uint4 v; ushort u[8]; } t;
        #pragma unroll
        for (int j = 0; j < 8; ++j) t.u[j] = f2bf(fp[(size_t)(c + j) * HWSZ]);
        *(uint4*)(op + c) = t.v;
    }
}

// ---------------------------------------------------------------------------
// One dense layer, in place on A (bf16, swizzled LDS). 8 waves = 2M x 4N.
// Wave tile 32 rows x N/4 cols, 16x16x32 MFMA with SWAPPED operands:
// mfma(w_frag, a_frag) -> C col = activation row, C rows = 4 consecutive
// output columns per lane -> packed ds_write_b64 writeback (vs 8x b16).
// B-fragments (weights) load directly global->VGPR from fragment-packed wt.
// ---------------------------------------------------------------------------
template <int K, int N, bool RELU>
__device__ __forceinline__ void dense_layer(
    char* __restrict__ sA, const ushort* __restrict__ Wt,
    const float* __restrict__ Bg, int tid)
{
    constexpr int TN  = N / 64;        // 16-col tiles per wave
    constexpr int NCH = K / 64;        // 64-wide K chunks

    const int lane = tid & 63, wv = tid >> 6;
    const int wm = wv >> 2, wn = wv & 3;
    const int row0 = wm * 32;
    const int col0 = wn * (N / 4);
    const int lrow = lane & 15;
    const int lkb  = (lane >> 4) * 16;   // byte offset of this lane's 8 bf16 in k

    f32x4 acc[2][TN];
    #pragma unroll
    for (int tm = 0; tm < 2; ++tm)
        #pragma unroll
        for (int tn = 0; tn < TN; ++tn) acc[tm][tn] = (f32x4){0.f, 0.f, 0.f, 0.f};

    const char* wbase = (const char*)Wt + (size_t)lane * 16;

    for (int c = 0; c < NCH; ++c) {
        #pragma unroll
        for (int ks = 0; ks < 64; ks += 32) {
            const int cb = (c * 64 + ks) * 2 + lkb;
            const bf16x8 a0 = *(const bf16x8*)(sA + swA(row0 +      lrow, cb));
            const bf16x8 a1 = *(const bf16x8*)(sA + swA(row0 + 16 + lrow, cb));
            #pragma unroll
            for (int tn = 0; tn < TN; ++tn) {
                const int tile = c * ((N >> 4) * 2) + ((col0 >> 4) + tn) * 2 + (ks >> 5);
                const bf16x8 bw = *(const bf16x8*)(wbase + tile * 1024);
                // swapped: C[i=ncol][j=actrow]
                acc[0][tn] = __builtin_amdgcn_mfma_f32_16x16x32_bf16(bw, a0, acc[0][tn], 0, 0, 0);
                acc[1][tn] = __builtin_amdgcn_mfma_f32_16x16x32_bf16(bw, a1, acc[1][tn], 0, 0, 0);
            }
        }
    }
    __syncthreads();   // all waves done reading A -> safe in-place writeback

    // writeback: lane holds row = row0+tm*16+lrow, cols = col0+tn*16+(lane>>4)*4+{0..3}
    #pragma unroll
    for (int tn = 0; tn < TN; ++tn) {
        const int colb = col0 + tn * 16 + (lane >> 4) * 4;
        const float4 b4 = *(const float4*)(Bg + colb);
        #pragma unroll
        for (int tm = 0; tm < 2; ++tm) {
            float v0 = acc[tm][tn][0] + b4.x;
            float v1 = acc[tm][tn][1] + b4.y;
            float v2 = acc[tm][tn][2] + b4.z;
            float v3 = acc[tm][tn][3] + b4.w;
            if (RELU) {
                v0 = fmaxf(v0, 0.f); v1 = fmaxf(v1, 0.f);
                v2 = fmaxf(v2, 0.f); v3 = fmaxf(v3, 0.f);
            }
            uint2 pk;
            pk.x = cvtpk(v0, v1);
            pk.y = cvtpk(v2, v3);
            const int row = row0 + tm * 16 + lrow;
            *(uint2*)(sA + swA(row, colb * 2)) = pk;
        }
    }
    __syncthreads();
}

// ---------------------------------------------------------------------------
// Fused: taps + PE MLP + gather-add + encoder MLP + softmax + output
// ---------------------------------------------------------------------------
template <bool USE_WS>
__global__ __launch_bounds__(512, 8) void fused_kernel(
    const float* __restrict__ depth, const float* __restrict__ feat,
    const float* __restrict__ coord,
    const float* __restrict__ pb0, const float* __restrict__ pb1,
    const float* __restrict__ pb2,
    const float* __restrict__ eb0, const float* __restrict__ eb1,
    const float* __restrict__ eb2,
    const float* __restrict__ ew3, const float* __restrict__ eb3,
    const ushort* __restrict__ wt,
    const ushort* __restrict__ nhwc, const float* __restrict__ xyws,
    float* __restrict__ out)
{
    extern __shared__ char lds[];
    char*  sA   = lds + OFF_A;
    int*   sTap = (int*)(lds + OFF_TAP);
    float* sPxy = (float*)(lds + OFF_PXY);
    float* sE3  = (float*)(lds + OFF_E3);

    const int tid  = threadIdx.x;
    const int row0g = blockIdx.x * ROWS;
    const int b     = row0g >> 17;   // QQ = 2^17, ROWS | QQ

    // stage final-layer weights (64x4 f32)
    if (tid < 256) sE3[tid] = ew3[tid];

    // zero A cols 0..63 (pe0 K padded 8->64); swizzle permutes within bytes 0..127
    {
        const int r = tid >> 3, c16 = tid & 7;
        uint4 z; z.x = z.y = z.z = z.w = 0u;
        *(uint4*)(sA + r * ASTR_B + c16 * 16) = z;
    }
    __syncthreads();

    // taps + rel coords + pred_xy; fp32, contraction OFF (match numpy rounding)
    if (tid < 256) {
        #pragma clang fp contract(off)
        const int r = tid >> 2, s = tid & 3;
        const int row = row0g + r;
        const float cy = coord[row * 2 + 0];
        const float cx = coord[row * 2 + 1];
        const float offy = (s < 2) ? -1.f : 1.f;
        const float offx = (s & 1) ? 1.f : -1.f;
        const float rx = 1.f / (float)HH, ry = 1.f / (float)WWID;
        float ccy = cy + (offy * rx + 1e-6f);
        float ccx = cx + (offx * ry + 1e-6f);
        ccy = fminf(fmaxf(ccy, -1.f + 1e-6f), 1.f - 1e-6f);
        ccx = fminf(fmaxf(ccx, -1.f + 1e-6f), 1.f - 1e-6f);
        int iy = (int)rintf(((ccy + 1.f) * (float)HH - 1.f) * 0.5f);
        int ix = (int)rintf(((ccx + 1.f) * (float)WWID - 1.f) * 0.5f);
        iy = min(max(iy, 0), HH - 1);
        ix = min(max(ix, 0), WWID - 1);
        const float qcy = -1.f + (2.f * (float)iy + 1.f) / (float)HH;
        const float qcx = -1.f + (2.f * (float)ix + 1.f) / (float)WWID;
        *(ushort*)(sA + swA(r, s * 4 + 0)) = f2bf((cy - qcy) * (float)HH);
        *(ushort*)(sA + swA(r, s * 4 + 2)) = f2bf((cx - qcx) * (float)WWID);
        const int tap = iy * WWID + ix;
        sTap[r * 4 + s] = tap;
        float px;
        if (USE_WS) {
            px = xyws[b * HWSZ + tap];
        } else {
            const float d1 = depth[(b * 3 + 1) * HWSZ + tap];
            const float d2 = depth[(b * 3 + 2) * HWSZ + tap];
            px = sqrtf(d1 * d1 + d2 * d2);
        }
        sPxy[r * 4 + s] = px;
    }
    __syncthreads();

    // PE MLP (rel coords in A cols 0..7, zero-padded to 64)
    dense_layer<64,  64,  true >(sA, wt + WOFF_PE0, pb0, tid);
    dense_layer<64,  128, true >(sA, wt + WOFF_PE1, pb1, tid);
    dense_layer<128, 256, false>(sA, wt + WOFF_PE2, pb2, tid);

    // gather-add q_feat: A[r][s*64+c] += feat[b,c,tap]
    {
        const int r = tid >> 3, h = tid & 7;
        const int s = h >> 1, half = h & 1;
        const int tap = sTap[r * 4 + s];
        const int cb0 = s * 128 + half * 64;   // byte offset of 32 channels
        if (USE_WS) {
            const ushort* src = nhwc + ((size_t)b * HWSZ + tap) * CC + half * 32;
            #pragma unroll
            for (int g = 0; g < 4; ++g) {
                char* dp = sA + swA(r, cb0 + g * 16);
                union { uint4 v; ushort u[8]; } a, d;
                a.v = *(const uint4*)(src + g * 8);
                d.v = *(uint4*)dp;
                float s0 = bf2f(a.u[0]) + bf2f(d.u[0]);
                float s1 = bf2f(a.u[1]) + bf2f(d.u[1]);
                float s2 = bf2f(a.u[2]) + bf2f(d.u[2]);
                float s3 = bf2f(a.u[3]) + bf2f(d.u[3]);
                float s4 = bf2f(a.u[4]) + bf2f(d.u[4]);
                float s5 = bf2f(a.u[5]) + bf2f(d.u[5]);
                float s6 = bf2f(a.u[6]) + bf2f(d.u[6]);
                float s7 = bf2f(a.u[7]) + bf2f(d.u[7]);
                uint4 o;
                o.x = cvtpk(s0, s1); o.y = cvtpk(s2, s3);
                o.z = cvtpk(s4, s5); o.w = cvtpk(s6, s7);
                *(uint4*)dp = o;
            }
        } else {
            const float* fp = feat + (size_t)b * CC * HWSZ + tap;
            #pragma unroll 8
            for (int c = 0; c < 32; ++c) {
                const int ch = half * 32 + c;
                ushort* p = (ushort*)(sA + swA(r, cb0 + c * 2));
                *p = f2bf(bf2f(*p) + fp[(size_t)ch * HWSZ]);
            }
        }
    }
    __syncthreads();

    // encoder MLP
    dense_layer<256, 256, true>(sA, wt + WOFF_E0, eb0, tid);
    dense_layer<256, 128, true>(sA, wt + WOFF_E1, eb1, tid);
    dense_layer<128, 64,  true>(sA, wt + WOFF_E2, eb2, tid);

    // final 64->4, softmax, weighted sum with pred_xy (4 threads per row)
    if (tid < 256) {
        const int r = tid >> 2, sub = tid & 3;
        float l0 = 0.f, l1 = 0.f, l2 = 0.f, l3 = 0.f;
        #pragma unroll
        for (int kk = 0; kk < 16; ++kk) {
            const int k = sub * 16 + kk;
            const float a = bf2f(*(const ushort*)(sA + swA(r, k * 2)));
            const float4 w = ((const float4*)sE3)[k];
            l0 = fmaf(a, w.x, l0);
            l1 = fmaf(a, w.y, l1);
            l2 = fmaf(a, w.z, l2);
            l3 = fmaf(a, w.w, l3);
        }
        #pragma unroll
        for (int m = 1; m <= 2; m <<= 1) {
            l0 += __shfl_xor(l0, m);
            l1 += __shfl_xor(l1, m);
            l2 += __shfl_xor(l2, m);
            l3 += __shfl_xor(l3, m);
        }
        if (sub == 0) {
            l0 += eb3[0]; l1 += eb3[1]; l2 += eb3[2]; l3 += eb3[3];
            const float m  = fmaxf(fmaxf(l0, l1), fmaxf(l2, l3));
            const float e0 = expf(l0 - m), e1 = expf(l1 - m);
            const float e2 = expf(l2 - m), e3 = expf(l3 - m);
            const float inv = 1.f / (e0 + e1 + e2 + e3);
            const float o = (sPxy[r * 4 + 0] * e0 + sPxy[r * 4 + 1] * e1 +
                             sPxy[r * 4 + 2] * e2 + sPxy[r * 4 + 3] * e3) * inv;
            out[row0g + r] = o;
        }
    }
}

// ---------------------------------------------------------------------------
extern "C" void kernel_launch(void* const* d_in, const int* in_sizes, int n_in,
                              void* d_out, int out_size, void* d_ws, size_t ws_size,
                              hipStream_t stream)
{
    const float* depth = (const float*)d_in[0];
    const float* feat  = (const float*)d_in[1];
    const float* coord = (const float*)d_in[2];
    const float* pw0 = (const float*)d_in[3],  *pb0 = (const float*)d_in[4];
    const float* pw1 = (const float*)d_in[5],  *pb1 = (const float*)d_in[6];
    const float* pw2 = (const float*)d_in[7],  *pb2 = (const float*)d_in[8];
    const float* ew0 = (const float*)d_in[9],  *eb0 = (const float*)d_in[10];
    const float* ew1 = (const float*)d_in[11], *eb1 = (const float*)d_in[12];
    const float* ew2 = (const float*)d_in[13], *eb2 = (const float*)d_in[14];
    const float* ew3 = (const float*)d_in[15], *eb3 = (const float*)d_in[16];
    float* out = (float*)d_out;

    const size_t nhwc_bytes = (size_t)NBATCH * HWSZ * CC * 2;
    const size_t xy_bytes   = (size_t)NBATCH * HWSZ * 4;
    const size_t wt_bytes   = (size_t)WTOTAL * 2;
    const bool use_ws = (ws_size >= nhwc_bytes + xy_bytes + wt_bytes);

    ushort* nhwc = (ushort*)d_ws;
    float*  xyws = (float*)((char*)d_ws + nhwc_bytes);
    ushort* wt   = use_ws ? (ushort*)((char*)d_ws + nhwc_bytes + xy_bytes)
                          : (ushort*)d_ws;

    WPack pack;
    pack.d[0] = { pw0, 8,   64,  6 };
    pack.d[1] = { pw1, 64,  128, 6 };
    pack.d[2] = { pw2, 128, 256, 7 };
    pack.d[3] = { ew0, 256, 256, 8 };
    pack.d[4] = { ew1, 256, 128, 8 };
    pack.d[5] = { ew2, 128, 64,  7 };
    prep_weights<<<WTOTAL / 256, 256, 0, stream>>>(pack, wt);

    const int nblocks = (NBATCH * QQ) / ROWS;   // 4096

    if (use_ws) {
        prep_feat<<<(NBATCH * HWSZ) / 256, 256, 0, stream>>>(depth, feat, nhwc, xyws);
        fused_kernel<true><<<nblocks, THREADS, LDS_BYTES, stream>>>(
            depth, feat, coord, pb0, pb1, pb2, eb0, eb1, eb2, ew3, eb3,
            wt, nhwc, xyws, out);
    } else {
        fused_kernel<false><<<nblocks, THREADS, LDS_BYTES, stream>>>(
            depth, feat, coord, pb0, pb1, pb2, eb0, eb1, eb2, ew3, eb3,
            wt, nhwc, xyws, out);
    }
}

// Round 8
// 156.428 us; speedup vs baseline: 2.1864x; 1.3791x over previous
//
#include <hip/hip_runtime.h>
#include <hip/hip_runtime_api.h>
#include <math.h>

#define NBATCH 2
#define QQ     131072
#define HH     64
#define WWID   2048
#define CC     64
#define HWSZ   (HH*WWID)   /* 131072 = 2^17 */

constexpr int ROWS    = 64;    // rows per block
constexpr int THREADS = 512;   // 8 waves, 2M x 4N wave grid

// A: 64 rows x 512 B (256 bf16), XOR-swizzled; byte ^= (row&7)<<4
constexpr int ASTR_B = 512;

// dynamic-LDS byte offsets
constexpr int OFF_A   = 0;                 // 32768 B
constexpr int OFF_TAP = 32768;             // tap[64][4] int  = 1024 B
constexpr int OFF_PXY = OFF_TAP + 1024;    // pxy[64][4] f32  = 1024 B
constexpr int OFF_E3  = OFF_PXY + 1024;    // ew3 64x4 f32    = 1024 B
constexpr int LDS_BYTES = OFF_E3 + 1024;   // 35840 B

// packed fragment-layout weight offsets in elements (Kp = K padded to 64)
constexpr int WOFF_PE0 = 0;       // N=64,  Kp=64   -> 4096
constexpr int WOFF_PE1 = 4096;    // N=128, Kp=64   -> 8192
constexpr int WOFF_PE2 = 12288;   // N=256, Kp=128  -> 32768
constexpr int WOFF_E0  = 45056;   // N=256, Kp=256  -> 65536
constexpr int WOFF_E1  = 110592;  // N=128, Kp=256  -> 32768
constexpr int WOFF_E2  = 143360;  // N=64,  Kp=128  -> 8192
constexpr int WTOTAL   = 151552;

typedef __attribute__((ext_vector_type(8))) short bf16x8;
typedef __attribute__((ext_vector_type(4))) float f32x4;

__device__ __forceinline__ ushort f2bf(float f) {
    union { float f; unsigned u; } x; x.f = f;
    unsigned r = x.u + 0x7fffu + ((x.u >> 16) & 1u);   // RNE
    return (ushort)(r >> 16);
}
__device__ __forceinline__ float bf2f(ushort h) {
    union { unsigned u; float f; } x; x.u = ((unsigned)h) << 16;
    return x.f;
}
// pack 2 f32 -> 2 bf16 in one u32 (RNE, gfx950). lo = cvt(a), hi = cvt(b).
__device__ __forceinline__ unsigned cvtpk(float a, float b) {
    unsigned r;
    asm("v_cvt_pk_bf16_f32 %0, %1, %2" : "=v"(r) : "v"(a), "v"(b));
    return r;
}

// swizzled A byte address (XOR flips bits 4-6 by row)
__device__ __forceinline__ int swA(int row, int colByte) {
    return row * ASTR_B + (colByte ^ ((row & 7) << 4));
}

// ---------------------------------------------------------------------------
// Weight prep: fp32 [K][N] -> bf16 MFMA-fragment-packed [chunks][tiles][512]
// tile = 16 cols x 32 k, lane-ordered: elem(lane,j) = W[k0+(lane>>4)*8+j][n0+(lane&15)]
// chunk = 64 k-wide: tiles ordered (n>>4)*2 + kk
// ---------------------------------------------------------------------------
struct WDesc { const float* src; int K; int N; int kshift; };  // Kp = 1<<kshift
struct WPack { WDesc d[6]; };

__global__ __launch_bounds__(256) void prep_weights(WPack p, ushort* __restrict__ dst)
{
    int e = blockIdx.x * 256 + threadIdx.x;
    int off = 0;
    #pragma unroll
    for (int L = 0; L < 6; ++L) {
        const int Kp = 1 << p.d[L].kshift;
        const int N  = p.d[L].N;
        const int sz = N * Kp;
        if (e < sz) {
            const int n = e / Kp;
            const int k = e & (Kp - 1);
            const float v = (k < p.d[L].K) ? p.d[L].src[(size_t)k * N + n] : 0.f;
            const int chunk = k >> 6;
            const int kk    = (k >> 5) & 1;
            const int tile  = chunk * ((N >> 4) * 2) + (n >> 4) * 2 + kk;
            const int lane  = (n & 15) + (((k >> 3) & 3) << 4);
            const int j     = k & 7;
            dst[off + tile * 512 + lane * 8 + j] = f2bf(v);
            return;
        }
        e -= sz; off += sz;
    }
}

// ---------------------------------------------------------------------------
// Feat prep: NCHW f32 -> NHWC bf16, plus xy = sqrt(d1^2+d2^2)
// ---------------------------------------------------------------------------
__global__ __launch_bounds__(256) void prep_feat(
    const float* __restrict__ depth, const float* __restrict__ feat,
    ushort* __restrict__ nhwc, float* __restrict__ xy)
{
    const int idx = blockIdx.x * 256 + threadIdx.x;
    const int b   = idx >> 17;
    const int yx  = idx & (HWSZ - 1);

    const float d1 = depth[(b * 3 + 1) * HWSZ + yx];
    const float d2 = depth[(b * 3 + 2) * HWSZ + yx];
    xy[idx] = sqrtf(d1 * d1 + d2 * d2);

    const float* fp = feat + (size_t)b * CC * HWSZ + yx;
    ushort* op = nhwc + (size_t)idx * CC;
    #pragma unroll
    for (int c = 0; c < CC; c += 8) {
        union { uint4 v; ushort u[8]; } t;
        #pragma unroll
        for (int j = 0; j < 8; ++j) t.u[j] = f2bf(fp[(size_t)(c + j) * HWSZ]);
        *(uint4*)(op + c) = t.v;
    }
}

// ---------------------------------------------------------------------------
// One dense layer, in place on A (bf16, swizzled LDS). 8 waves = 2M x 4N.
// Wave tile 32 rows x N/4 cols, 16x16x32 MFMA with SWAPPED operands:
// mfma(w_frag, a_frag) -> lane holds 4 consecutive output cols of one row
// -> packed ds_write_b64 writeback. B-fragments (weights) load directly
// global->VGPR from fragment-packed wt (L1/L2-hot).
// ---------------------------------------------------------------------------
template <int K, int N, bool RELU>
__device__ __forceinline__ void dense_layer(
    char* __restrict__ sA, const ushort* __restrict__ Wt,
    const float* __restrict__ Bg, int tid)
{
    constexpr int TN  = N / 64;        // 16-col tiles per wave
    constexpr int NCH = K / 64;        // 64-wide K chunks

    const int lane = tid & 63, wv = tid >> 6;
    const int wm = wv >> 2, wn = wv & 3;
    const int row0 = wm * 32;
    const int col0 = wn * (N / 4);
    const int lrow = lane & 15;
    const int lkb  = (lane >> 4) * 16;   // byte offset of this lane's 8 bf16 in k

    f32x4 acc[2][TN];
    #pragma unroll
    for (int tm = 0; tm < 2; ++tm)
        #pragma unroll
        for (int tn = 0; tn < TN; ++tn) acc[tm][tn] = (f32x4){0.f, 0.f, 0.f, 0.f};

    const char* wbase = (const char*)Wt + (size_t)lane * 16;

    for (int c = 0; c < NCH; ++c) {
        #pragma unroll
        for (int ks = 0; ks < 64; ks += 32) {
            const int cb = (c * 64 + ks) * 2 + lkb;
            const bf16x8 a0 = *(const bf16x8*)(sA + swA(row0 +      lrow, cb));
            const bf16x8 a1 = *(const bf16x8*)(sA + swA(row0 + 16 + lrow, cb));
            #pragma unroll
            for (int tn = 0; tn < TN; ++tn) {
                const int tile = c * ((N >> 4) * 2) + ((col0 >> 4) + tn) * 2 + (ks >> 5);
                const bf16x8 bw = *(const bf16x8*)(wbase + tile * 1024);
                // swapped: C[i=ncol][j=actrow]
                acc[0][tn] = __builtin_amdgcn_mfma_f32_16x16x32_bf16(bw, a0, acc[0][tn], 0, 0, 0);
                acc[1][tn] = __builtin_amdgcn_mfma_f32_16x16x32_bf16(bw, a1, acc[1][tn], 0, 0, 0);
            }
        }
    }
    __syncthreads();   // all waves done reading A -> safe in-place writeback

    // writeback: lane holds row = row0+tm*16+lrow, cols = col0+tn*16+(lane>>4)*4+{0..3}
    #pragma unroll
    for (int tn = 0; tn < TN; ++tn) {
        const int colb = col0 + tn * 16 + (lane >> 4) * 4;
        const float4 b4 = *(const float4*)(Bg + colb);
        #pragma unroll
        for (int tm = 0; tm < 2; ++tm) {
            float v0 = acc[tm][tn][0] + b4.x;
            float v1 = acc[tm][tn][1] + b4.y;
            float v2 = acc[tm][tn][2] + b4.z;
            float v3 = acc[tm][tn][3] + b4.w;
            if (RELU) {
                v0 = fmaxf(v0, 0.f); v1 = fmaxf(v1, 0.f);
                v2 = fmaxf(v2, 0.f); v3 = fmaxf(v3, 0.f);
            }
            uint2 pk;
            pk.x = cvtpk(v0, v1);
            pk.y = cvtpk(v2, v3);
            const int row = row0 + tm * 16 + lrow;
            *(uint2*)(sA + swA(row, colb * 2)) = pk;
        }
    }
    __syncthreads();
}

// ---------------------------------------------------------------------------
// Fused: taps + PE MLP + gather-add + encoder MLP + softmax + output
// __launch_bounds__(512, 4): 2 blocks/CU target -> 128-reg unified budget.
// (512,8) capped arch VGPRs at 32 -> ~340 MB/dispatch scratch spills (r7);
// need ~64 arch + 32 acc = 96.
// ---------------------------------------------------------------------------
template <bool USE_WS>
__global__ __launch_bounds__(512, 4) void fused_kernel(
    const float* __restrict__ depth, const float* __restrict__ feat,
    const float* __restrict__ coord,
    const float* __restrict__ pb0, const float* __restrict__ pb1,
    const float* __restrict__ pb2,
    const float* __restrict__ eb0, const float* __restrict__ eb1,
    const float* __restrict__ eb2,
    const float* __restrict__ ew3, const float* __restrict__ eb3,
    const ushort* __restrict__ wt,
    const ushort* __restrict__ nhwc, const float* __restrict__ xyws,
    float* __restrict__ out)
{
    extern __shared__ char lds[];
    char*  sA   = lds + OFF_A;
    int*   sTap = (int*)(lds + OFF_TAP);
    float* sPxy = (float*)(lds + OFF_PXY);
    float* sE3  = (float*)(lds + OFF_E3);

    const int tid  = threadIdx.x;
    const int row0g = blockIdx.x * ROWS;
    const int b     = row0g >> 17;   // QQ = 2^17, ROWS | QQ

    // stage final-layer weights (64x4 f32)
    if (tid < 256) sE3[tid] = ew3[tid];

    // zero A cols 0..63 (pe0 K padded 8->64); swizzle permutes within bytes 0..127
    {
        const int r = tid >> 3, c16 = tid & 7;
        uint4 z; z.x = z.y = z.z = z.w = 0u;
        *(uint4*)(sA + r * ASTR_B + c16 * 16) = z;
    }
    __syncthreads();

    // taps + rel coords + pred_xy; fp32, contraction OFF (match numpy rounding)
    if (tid < 256) {
        #pragma clang fp contract(off)
        const int r = tid >> 2, s = tid & 3;
        const int row = row0g + r;
        const float cy = coord[row * 2 + 0];
        const float cx = coord[row * 2 + 1];
        const float offy = (s < 2) ? -1.f : 1.f;
        const float offx = (s & 1) ? 1.f : -1.f;
        const float rx = 1.f / (float)HH, ry = 1.f / (float)WWID;
        float ccy = cy + (offy * rx + 1e-6f);
        float ccx = cx + (offx * ry + 1e-6f);
        ccy = fminf(fmaxf(ccy, -1.f + 1e-6f), 1.f - 1e-6f);
        ccx = fminf(fmaxf(ccx, -1.f + 1e-6f), 1.f - 1e-6f);
        int iy = (int)rintf(((ccy + 1.f) * (float)HH - 1.f) * 0.5f);
        int ix = (int)rintf(((ccx + 1.f) * (float)WWID - 1.f) * 0.5f);
        iy = min(max(iy, 0), HH - 1);
        ix = min(max(ix, 0), WWID - 1);
        const float qcy = -1.f + (2.f * (float)iy + 1.f) / (float)HH;
        const float qcx = -1.f + (2.f * (float)ix + 1.f) / (float)WWID;
        *(ushort*)(sA + swA(r, s * 4 + 0)) = f2bf((cy - qcy) * (float)HH);
        *(ushort*)(sA + swA(r, s * 4 + 2)) = f2bf((cx - qcx) * (float)WWID);
        const int tap = iy * WWID + ix;
        sTap[r * 4 + s] = tap;
        float px;
        if (USE_WS) {
            px = xyws[b * HWSZ + tap];
        } else {
            const float d1 = depth[(b * 3 + 1) * HWSZ + tap];
            const float d2 = depth[(b * 3 + 2) * HWSZ + tap];
            px = sqrtf(d1 * d1 + d2 * d2);
        }
        sPxy[r * 4 + s] = px;
    }
    __syncthreads();

    // PE MLP (rel coords in A cols 0..7, zero-padded to 64)
    dense_layer<64,  64,  true >(sA, wt + WOFF_PE0, pb0, tid);
    dense_layer<64,  128, true >(sA, wt + WOFF_PE1, pb1, tid);
    dense_layer<128, 256, false>(sA, wt + WOFF_PE2, pb2, tid);

    // gather-add q_feat: A[r][s*64+c] += feat[b,c,tap]
    {
        const int r = tid >> 3, h = tid & 7;
        const int s = h >> 1, half = h & 1;
        const int tap = sTap[r * 4 + s];
        const int cb0 = s * 128 + half * 64;   // byte offset of 32 channels
        if (USE_WS) {
            const ushort* src = nhwc + ((size_t)b * HWSZ + tap) * CC + half * 32;
            #pragma unroll
            for (int g = 0; g < 4; ++g) {
                char* dp = sA + swA(r, cb0 + g * 16);
                union { uint4 v; ushort u[8]; } a, d;
                a.v = *(const uint4*)(src + g * 8);
                d.v = *(uint4*)dp;
                float s0 = bf2f(a.u[0]) + bf2f(d.u[0]);
                float s1 = bf2f(a.u[1]) + bf2f(d.u[1]);
                float s2 = bf2f(a.u[2]) + bf2f(d.u[2]);
                float s3 = bf2f(a.u[3]) + bf2f(d.u[3]);
                float s4 = bf2f(a.u[4]) + bf2f(d.u[4]);
                float s5 = bf2f(a.u[5]) + bf2f(d.u[5]);
                float s6 = bf2f(a.u[6]) + bf2f(d.u[6]);
                float s7 = bf2f(a.u[7]) + bf2f(d.u[7]);
                uint4 o;
                o.x = cvtpk(s0, s1); o.y = cvtpk(s2, s3);
                o.z = cvtpk(s4, s5); o.w = cvtpk(s6, s7);
                *(uint4*)dp = o;
            }
        } else {
            const float* fp = feat + (size_t)b * CC * HWSZ + tap;
            #pragma unroll 8
            for (int c = 0; c < 32; ++c) {
                const int ch = half * 32 + c;
                ushort* p = (ushort*)(sA + swA(r, cb0 + c * 2));
                *p = f2bf(bf2f(*p) + fp[(size_t)ch * HWSZ]);
            }
        }
    }
    __syncthreads();

    // encoder MLP
    dense_layer<256, 256, true>(sA, wt + WOFF_E0, eb0, tid);
    dense_layer<256, 128, true>(sA, wt + WOFF_E1, eb1, tid);
    dense_layer<128, 64,  true>(sA, wt + WOFF_E2, eb2, tid);

    // final 64->4, softmax, weighted sum with pred_xy (4 threads per row)
    if (tid < 256) {
        const int r = tid >> 2, sub = tid & 3;
        float l0 = 0.f, l1 = 0.f, l2 = 0.f, l3 = 0.f;
        #pragma unroll
        for (int kk = 0; kk < 16; ++kk) {
            const int k = sub * 16 + kk;
            const float a = bf2f(*(const ushort*)(sA + swA(r, k * 2)));
            const float4 w = ((const float4*)sE3)[k];
            l0 = fmaf(a, w.x, l0);
            l1 = fmaf(a, w.y, l1);
            l2 = fmaf(a, w.z, l2);
            l3 = fmaf(a, w.w, l3);
        }
        #pragma unroll
        for (int m = 1; m <= 2; m <<= 1) {
            l0 += __shfl_xor(l0, m);
            l1 += __shfl_xor(l1, m);
            l2 += __shfl_xor(l2, m);
            l3 += __shfl_xor(l3, m);
        }
        if (sub == 0) {
            l0 += eb3[0]; l1 += eb3[1]; l2 += eb3[2]; l3 += eb3[3];
            const float m  = fmaxf(fmaxf(l0, l1), fmaxf(l2, l3));
            const float e0 = expf(l0 - m), e1 = expf(l1 - m);
            const float e2 = expf(l2 - m), e3 = expf(l3 - m);
            const float inv = 1.f / (e0 + e1 + e2 + e3);
            const float o = (sPxy[r * 4 + 0] * e0 + sPxy[r * 4 + 1] * e1 +
                             sPxy[r * 4 + 2] * e2 + sPxy[r * 4 + 3] * e3) * inv;
            out[row0g + r] = o;
        }
    }
}

// ---------------------------------------------------------------------------
extern "C" void kernel_launch(void* const* d_in, const int* in_sizes, int n_in,
                              void* d_out, int out_size, void* d_ws, size_t ws_size,
                              hipStream_t stream)
{
    const float* depth = (const float*)d_in[0];
    const float* feat  = (const float*)d_in[1];
    const float* coord = (const float*)d_in[2];
    const float* pw0 = (const float*)d_in[3],  *pb0 = (const float*)d_in[4];
    const float* pw1 = (const float*)d_in[5],  *pb1 = (const float*)d_in[6];
    const float* pw2 = (const float*)d_in[7],  *pb2 = (const float*)d_in[8];
    const float* ew0 = (const float*)d_in[9],  *eb0 = (const float*)d_in[10];
    const float* ew1 = (const float*)d_in[11], *eb1 = (const float*)d_in[12];
    const float* ew2 = (const float*)d_in[13], *eb2 = (const float*)d_in[14];
    const float* ew3 = (const float*)d_in[15], *eb3 = (const float*)d_in[16];
    float* out = (float*)d_out;

    const size_t nhwc_bytes = (size_t)NBATCH * HWSZ * CC * 2;
    const size_t xy_bytes   = (size_t)NBATCH * HWSZ * 4;
    const size_t wt_bytes   = (size_t)WTOTAL * 2;
    const bool use_ws = (ws_size >= nhwc_bytes + xy_bytes + wt_bytes);

    ushort* nhwc = (ushort*)d_ws;
    float*  xyws = (float*)((char*)d_ws + nhwc_bytes);
    ushort* wt   = use_ws ? (ushort*)((char*)d_ws + nhwc_bytes + xy_bytes)
                          : (ushort*)d_ws;

    WPack pack;
    pack.d[0] = { pw0, 8,   64,  6 };
    pack.d[1] = { pw1, 64,  128, 6 };
    pack.d[2] = { pw2, 128, 256, 7 };
    pack.d[3] = { ew0, 256, 256, 8 };
    pack.d[4] = { ew1, 256, 128, 8 };
    pack.d[5] = { ew2, 128, 64,  7 };
    prep_weights<<<WTOTAL / 256, 256, 0, stream>>>(pack, wt);

    const int nblocks = (NBATCH * QQ) / ROWS;   // 4096

    if (use_ws) {
        prep_feat<<<(NBATCH * HWSZ) / 256, 256, 0, stream>>>(depth, feat, nhwc, xyws);
        fused_kernel<true><<<nblocks, THREADS, LDS_BYTES, stream>>>(
            depth, feat, coord, pb0, pb1, pb2, eb0, eb1, eb2, ew3, eb3,
            wt, nhwc, xyws, out);
    } else {
        fused_kernel<false><<<nblocks, THREADS, LDS_BYTES, stream>>>(
            depth, feat, coord, pb0, pb1, pb2, eb0, eb1, eb2, ew3, eb3,
            wt, nhwc, xyws, out);
    }
}